// Round 5
// baseline (225.755 us; speedup 1.0000x reference)
//
#include <hip/hip_runtime.h>

typedef unsigned short u16;
typedef __attribute__((ext_vector_type(8))) short short8;
typedef __attribute__((ext_vector_type(4))) float float4v;
typedef __attribute__((ext_vector_type(4))) int int4v;
typedef __attribute__((ext_vector_type(2))) int int2v;

#define EPS 1e-5f
#define NC 256
#define NT 251
#define NF 7
#define NSP 1757   // NF*NT
#define NB 32

// workspace layout (float offsets)
#define OFF_QEC 0
#define OFF_KEC 256
#define OFF_QEF 512
#define OFF_KEF 768
#define OFF_QET 1024
#define OFF_KET 1280
#define OFF_VSC 1536
#define OFF_VOF 1792
#define OFF_CONST 2048   // [0..5]=q/k consts c,f,t  [6]=s_c [7]=s_f [8]=s_t
#define OFF_DC 2064      // 256
#define OFF_DF 2320      // 256 (251 used)
#define OFF_DT 2576      // 16 (7 used)
#define WS_END 2592
// fused-t staging (old layout [b][t][f] for fallback; new path uses [b][sp])
#define OFF_QT 2592            // 56320
#define OFF_KT (OFF_QT+56320)  // 56320
#define WS2_END (OFF_KT+56320) // 115232 floats
// pre-tiled bf16 v_w in MFMA LDS layout
#define OFF_WB16 WS2_END
#define WS3_END (WS2_END+32768) // 148000 floats
// new-path staging: qf/kf [b][sp], qc/kc [n][ch]
#define OFF_QF2 WS3_END              // 56320
#define OFF_KF2 (OFF_QF2+56320)      // 56320
#define OFF_QCS (OFF_KF2+56320)      // 57344
#define OFF_KCS (OFF_QCS+57344)      // 57344
#define WS4_END (OFF_KCS+57344)      // 375328 floats ≈ 1.43 MB
// bf16 x image in main's B-fragment order: [b][nchunk14][ks8][kg8][w256] u32
#define OFF_XB16 WS4_END
#define XB16_U32 (448*16384)         // 7340032 u32
#define WS5_END (OFF_XB16 + XB16_U32) // 7715360 floats ≈ 29.4 MB

// Xs swizzle for fallback main_kernel LDS (4-way -> 2-way on b64 frag reads)
#define XSW(kg, w) ((kg)*256 + ((w) ^ ((((kg)>>1)&3)<<3)))

__device__ __forceinline__ u16 f2b(float f) {   // fp32 -> bf16 RNE
    unsigned int u = __float_as_uint(f);
    return (u16)((u + 0x7FFFu + ((u >> 16) & 1u)) >> 16);
}
__device__ __forceinline__ unsigned int pk2(float a, float b) {
    return (unsigned int)f2b(a) | ((unsigned int)f2b(b) << 16);
}

// ---------------------------------------------------------------- prep
__global__ __launch_bounds__(256) void prep_kernel(
    const float* qc_w, const float* qc_bn, const float* kc_w, const float* kc_bn, const float* lc_bn,
    const float* qf_w, const float* qf_bn, const float* kf_w, const float* kf_bn, const float* lf_bn,
    const float* qt_w, const float* qt_bn, const float* kt_w, const float* kt_bn, const float* lt_bn,
    const float* v_b, const float* v_bn, const float* v_w, float* ws)
{
    int tid = threadIdx.x;
    int blk = blockIdx.x;
    __shared__ float sc[256];
    __shared__ float red[256];
    if (blk < 24) {
        int m = blk >> 2, j = blk & 3;
        const float* w; const float* bn; float* out; int O;
        switch (m) {
            case 0: w=qc_w; bn=qc_bn; out=ws+OFF_QEC; O=NT; break;
            case 1: w=kc_w; bn=kc_bn; out=ws+OFF_KEC; O=NT; break;
            case 2: w=qf_w; bn=qf_bn; out=ws+OFF_QEF; O=NC; break;
            case 3: w=kf_w; bn=kf_bn; out=ws+OFF_KEF; O=NC; break;
            case 4: w=qt_w; bn=qt_bn; out=ws+OFF_QET; O=NC; break;
            default: w=kt_w; bn=kt_bn; out=ws+OFF_KET; O=NC; break;
        }
        if (tid < O) sc[tid] = bn[tid] * rsqrtf(bn[3*O+tid] + EPS);
        __syncthreads();
        int tl = tid & 63, kc4 = tid >> 6;
        int t = j*64 + tl;
        float acc = 0.f;
        if (t < O) {
            #pragma unroll 8
            for (int o = kc4; o < O; o += 4)
                acc = fmaf(sc[o], w[(size_t)o*O + t], acc);
        }
        red[tid] = acc;
        __syncthreads();
        if (tid < 64) {
            int tt = j*64 + tid;
            if (tt < O)
                out[tt] = (red[tid] + red[tid+64] + red[tid+128] + red[tid+192]) / (float)O;
        }
        if (j == 0) {
            float bs = 0.f;
            if (tid < O) bs = bn[O+tid] - bn[2*O+tid]*sc[tid];
            __syncthreads();
            red[tid] = bs; __syncthreads();
            for (int s2 = 128; s2 > 0; s2 >>= 1) { if (tid < s2) red[tid] += red[tid+s2]; __syncthreads(); }
            if (tid == 0) ws[OFF_CONST+m] = red[0] / (float)O;
        }
    } else if (blk == 24) {
        if (tid < NC) {
            float s = v_bn[tid] * rsqrtf(v_bn[3*NC+tid] + EPS);
            ws[OFF_VSC+tid] = s;
            ws[OFF_VOF+tid] = v_bn[NC+tid] - v_bn[2*NC+tid]*s + v_b[tid]*s;
        }
        if (tid == 0) {
            ws[OFF_CONST+6] = lc_bn[0] * rsqrtf(lc_bn[3] + EPS);
            ws[OFF_CONST+7] = lf_bn[0] * rsqrtf(lf_bn[3] + EPS);
            ws[OFF_CONST+8] = lt_bn[0] * rsqrtf(lt_bn[3] + EPS);
        }
        for (int i = tid; i < WS_END - OFF_DC; i += 256) ws[OFF_DC + i] = 0.f;
    } else {
        // blocks 25..32: tile v_w -> bf16 MFMA layout. Coalesced float4 reads,
        // scattered 8B writes.
        u16* wb = (u16*)(ws + OFF_WB16);
        int base = (blk - 25) * 8192;   // elements of v_w
        for (int i4 = tid; i4 < 2048; i4 += 256) {
            int e = base + i4*4;
            int o = e >> 8, k = e & 255;
            float4v v = *(const float4v*)(v_w + e);
            u16 h0 = f2b(v.x), h1 = f2b(v.y), h2 = f2b(v.z), h3 = f2b(v.w);
            int r = ((o>>7)<<3) | (k>>5);
            int q = (((o>>4)&7)<<9) | (((k>>3)&3)<<7) | ((o&15)<<3) | (k&7);
            unsigned long long pk = (unsigned long long)h0 | ((unsigned long long)h1<<16)
                                  | ((unsigned long long)h2<<32) | ((unsigned long long)h3<<48);
            *(unsigned long long*)&wb[(r<<12) | q] = pk;
        }
    }
}

// --------------- qv/kv computation, fully parallel, staged to ws
// blocks 0..1791  : c-part -> QCS/KCS (conflict-free LDS reduce)
// blocks 1792..2239: ft-part -> QF2/KF2/QT/KT (+ bf16 x-image if pack)
__global__ __launch_bounds__(512) void qv_kernel(const float* __restrict__ x,
                                                 float* __restrict__ ws, int pack)
{
    __shared__ float lds[9760];    // c: tile[32][257]=8224 | qe 8224 | ke 8480 | pq 8736 | pk 9248
    int tid = threadIdx.x;
    int blk = blockIdx.x;
    const float* cst = ws + OFF_CONST;

    if (blk < 1792) {
        // ---------- c-part ----------
        int n = blk >> 3, cb = blk & 7;
        int b = n / NF, f = n % NF;
        const float* xb = x + (size_t)b*NC*NSP + (size_t)f*NT + (size_t)(cb*32)*NSP;
        if (tid < NT) lds[8224+tid] = ws[OFF_QEC+tid];
        else if (tid >= 256 && tid < 256+NT) lds[8480+tid-256] = ws[OFF_KEC+tid-256];
        int lr = tid >> 8, lane = tid & 255;
        #pragma unroll 4
        for (int i = 0; i < 16; ++i) {
            int r = 2*i + lr;
            if (lane < NT) lds[r*257 + lane] = xb[(size_t)r*NSP + lane];
        }
        __syncthreads();
        // reduce: thread (r in 0..31, seg in 0..15); banks (r+t)%32 -> <=2-way (free)
        int r = tid & 31, seg = tid >> 5;
        int t0 = seg*16, t1 = (seg == 15) ? NT : t0+16;
        float qa = 0.f, ka = 0.f;
        #pragma unroll 4
        for (int t = t0; t < t1; ++t) {
            float xv = lds[r*257 + t];
            qa = fmaf(lds[8224+t], xv, qa);
            ka = fmaf(lds[8480+t], xv, ka);
        }
        lds[8736 + seg*32 + r] = qa;   // bank = r: conflict-free
        lds[9248 + seg*32 + r] = ka;
        __syncthreads();
        if (tid < 64) {
            int rr = tid & 31, which = tid >> 5;
            int base = 8736 + which*512 + rr;
            float s = 0.f;
            #pragma unroll
            for (int sg = 0; sg < 16; ++sg) s += lds[base + sg*32];
            int ch = cb*32 + rr;
            if (which == 0) ws[OFF_QCS + n*256 + ch] = s;
            else            ws[OFF_KCS + n*256 + ch] = s;
        }
    } else {
        // ---------- ft-part ----------
        int fb = blk - 1792;             // 0..447
        int b = fb / 14, nchunk = fb % 14;
        int n0 = nchunk * 128;
        int spg = tid & 31, chg = tid >> 5;   // 32 sp-groups x 16 ch-groups
        if (tid < 256) { lds[5120+tid] = ws[OFF_QEF+tid]; lds[5632+tid] = ws[OFF_QET+tid]; }
        else { int u = tid-256; lds[5376+u] = ws[OFF_KEF+u]; lds[5888+u] = ws[OFF_KET+u]; }
        __syncthreads();
        const size_t xbase = (size_t)b*NC*NSP;
        int sp0 = n0 + spg*4;
        bool full = (sp0 + 3 < NSP);
        unsigned int* ximg = nullptr;
        if (pack) ximg = (unsigned int*)(ws + OFF_XB16) + (size_t)(b*14 + nchunk)*16384;

        float qf[4]={0,0,0,0}, kf[4]={0,0,0,0}, qt[4]={0,0,0,0}, kt[4]={0,0,0,0};
        #pragma unroll
        for (int ii = 0; ii < 4; ++ii) {
            int ch0 = chg*16 + ii*4;
            float xv4[4][4];
            #pragma unroll
            for (int cc = 0; cc < 4; ++cc) {
                int ch = ch0 + cc;
                const float* xr = x + xbase + (size_t)ch*NSP + sp0;
                if (full) {
                    xv4[cc][0]=xr[0]; xv4[cc][1]=xr[1]; xv4[cc][2]=xr[2]; xv4[cc][3]=xr[3];
                } else {
                    #pragma unroll
                    for (int j = 0; j < 4; ++j) xv4[cc][j] = (sp0+j < NSP) ? xr[j] : 0.f;
                }
                float eqf = lds[5120+ch], ekf = lds[5376+ch];
                float eqt = lds[5632+ch], ekt = lds[5888+ch];
                #pragma unroll
                for (int j = 0; j < 4; ++j) {
                    qf[j] = fmaf(eqf, xv4[cc][j], qf[j]);
                    kf[j] = fmaf(ekf, xv4[cc][j], kf[j]);
                    qt[j] = fmaf(eqt, xv4[cc][j], qt[j]);
                    kt[j] = fmaf(ekt, xv4[cc][j], kt[j]);
                }
            }
            if (pack) {
                int kgsg = ch0 >> 2;
                int ks = kgsg >> 3, kgl = kgsg & 7;
                unsigned int* dst = ximg + ks*2048 + kgl*256 + spg*8;
                unsigned int pk[8];
                #pragma unroll
                for (int i = 0; i < 4; ++i) {
                    pk[i*2+0] = pk2(xv4[0][i], xv4[1][i]);
                    pk[i*2+1] = pk2(xv4[2][i], xv4[3][i]);
                }
                *(int4v*)&dst[0] = *(int4v*)&pk[0];
                *(int4v*)&dst[4] = *(int4v*)&pk[4];
            }
        }
        // fold chg-pairs across wave halves (lanes 0-31 <-> 32-63)
        #pragma unroll
        for (int j = 0; j < 4; ++j) {
            qf[j] += __shfl_xor(qf[j], 32);
            kf[j] += __shfl_xor(kf[j], 32);
            qt[j] += __shfl_xor(qt[j], 32);
            kt[j] += __shfl_xor(kt[j], 32);
        }
        int wv = tid >> 6, ln = tid & 63;
        if (ln < 32) {
            // layout [v(16)][wv(8)][spg(32)]: bank = spg -> conflict-free
            #pragma unroll
            for (int j = 0; j < 4; ++j) {
                lds[(j)*256     + wv*32 + ln] = qf[j];
                lds[(4+j)*256   + wv*32 + ln] = kf[j];
                lds[(8+j)*256   + wv*32 + ln] = qt[j];
                lds[(12+j)*256  + wv*32 + ln] = kt[j];
            }
        }
        __syncthreads();
        if (tid < 32) {
            float acc[16];
            #pragma unroll
            for (int v = 0; v < 16; ++v) {
                float s = 0.f;
                #pragma unroll
                for (int w = 0; w < 8; ++w) s += lds[v*256 + w*32 + tid];
                acc[v] = s;
            }
            int sp0w = n0 + tid*4;
            #pragma unroll
            for (int j = 0; j < 4; ++j) {
                if (sp0w + j < NSP) {
                    size_t o = (size_t)b*1760 + sp0w + j;
                    ws[OFF_QF2 + o] = acc[j]    + cst[2];
                    ws[OFF_KF2 + o] = acc[4+j]  + cst[3];
                    ws[OFF_QT  + o] = acc[8+j]  + cst[4];
                    ws[OFF_KT  + o] = acc[12+j] + cst[5];
                }
            }
        }
    }
}

// --------------- all three diag softmaxes from staged q/k
__global__ __launch_bounds__(256) void sm_kernel(float* __restrict__ ws)
{
    __shared__ float kv[NC];
    __shared__ float kv2[NT];
    __shared__ float dt_acc[NF];
    int tid = threadIdx.x, blk = blockIdx.x;
    const float* cst = ws + OFF_CONST;

    if (blk < 224) {
        int b = blk / NF, f = blk % NF;
        float qcv = ws[OFF_QCS + blk*256 + tid] + cst[0];
        float kcv = ws[OFF_KCS + blk*256 + tid] + cst[1];
        kv[tid] = kcv;
        float qfv = 0.f, kfv = 0.f;
        if (tid < NT) {
            size_t o = (size_t)b*1760 + f*NT + tid;
            qfv = ws[OFF_QF2 + o];
            kfv = ws[OFF_KF2 + o];
            kv2[tid] = kfv;
        }
        __syncthreads();
        {   // c diag softmax
            float s = cst[6];
            float qi = s * qcv;
            float m0=-1e30f, m1=-1e30f, m2=-1e30f, m3=-1e30f;
            #pragma unroll 2
            for (int jj = 0; jj < NC; jj += 4) {
                m0 = fmaxf(m0, qi*kv[jj]);
                m1 = fmaxf(m1, qi*kv[jj+1]);
                m2 = fmaxf(m2, qi*kv[jj+2]);
                m3 = fmaxf(m3, qi*kv[jj+3]);
            }
            float m = fmaxf(fmaxf(m0,m1), fmaxf(m2,m3));
            float d0=0.f, d1=0.f, d2=0.f, d3=0.f;
            #pragma unroll 2
            for (int jj = 0; jj < NC; jj += 4) {
                d0 += __expf(qi*kv[jj]   - m);
                d1 += __expf(qi*kv[jj+1] - m);
                d2 += __expf(qi*kv[jj+2] - m);
                d3 += __expf(qi*kv[jj+3] - m);
            }
            float den = (d0+d1)+(d2+d3);
            atomicAdd(&ws[OFF_DC + tid], __expf(qi*kcv - m)/den);
        }
        if (tid < NT) {   // f diag softmax
            float s = cst[7];
            float qi = s * qfv;
            float m0=-1e30f, m1=-1e30f, m2=-1e30f, m3=-1e30f;
            int jj = 0;
            #pragma unroll 2
            for (; jj + 3 < NT; jj += 4) {
                m0 = fmaxf(m0, qi*kv2[jj]);
                m1 = fmaxf(m1, qi*kv2[jj+1]);
                m2 = fmaxf(m2, qi*kv2[jj+2]);
                m3 = fmaxf(m3, qi*kv2[jj+3]);
            }
            for (; jj < NT; ++jj) m0 = fmaxf(m0, qi*kv2[jj]);
            float m = fmaxf(fmaxf(m0,m1), fmaxf(m2,m3));
            float d0=0.f, d1=0.f, d2=0.f, d3=0.f;
            jj = 0;
            #pragma unroll 2
            for (; jj + 3 < NT; jj += 4) {
                d0 += __expf(qi*kv2[jj]   - m);
                d1 += __expf(qi*kv2[jj+1] - m);
                d2 += __expf(qi*kv2[jj+2] - m);
                d3 += __expf(qi*kv2[jj+3] - m);
            }
            for (; jj < NT; ++jj) d0 += __expf(qi*kv2[jj] - m);
            float den = (d0+d1)+(d2+d3);
            atomicAdd(&ws[OFF_DF + tid], __expf(qi*kfv - m)/den);
        }
    } else {
        int b = blk - 224;
        if (tid < NF) dt_acc[tid] = 0.f;
        __syncthreads();
        if (tid < NT) {
            float s = cst[8];
            float q[NF], k[NF];
            #pragma unroll
            for (int i = 0; i < NF; ++i) {
                size_t o = (size_t)b*1760 + i*NT + tid;
                q[i] = ws[OFF_QT + o];
                k[i] = ws[OFF_KT + o];
            }
            #pragma unroll
            for (int i = 0; i < NF; ++i) {
                float qi = s * q[i];
                float m = -1e30f;
                #pragma unroll
                for (int j = 0; j < NF; ++j) m = fmaxf(m, qi*k[j]);
                float den = 0.f;
                #pragma unroll
                for (int j = 0; j < NF; ++j) den += __expf(qi*k[j] - m);
                atomicAdd(&dt_acc[i], __expf(qi*k[i] - m)/den);
            }
        }
        __syncthreads();
        if (tid < NF) atomicAdd(&ws[OFF_DT + tid], dt_acc[tid]);
    }
}

// ------------ OLD-PATH kernels (fallback when ws too small) ------------
__global__ __launch_bounds__(512) void qkt_kernel(const float* __restrict__ x,
                                                  float* __restrict__ ws, int fuse_t)
{
    __shared__ float kv[NC];
    __shared__ float p0[512], p1[512], p2[512], p3[512];
    int tid = threadIdx.x;
    int bid = blockIdx.x;
    int n = bid >> 1, role = bid & 1;
    int b = n / NF, f = n % NF;
    const float* xb = x + (size_t)b*NC*NSP + (size_t)f*NT;
    const float* cst = ws + OFF_CONST;
    int half = tid >> 8, lid = tid & 255;

    if (role == 0) {
        const float* xrow = xb + (size_t)lid*NSP;
        const float* qeC = ws + OFF_QEC;  const float* keC = ws + OFF_KEC;
        float qc = 0.f, kc = 0.f;
        int t0 = half ? 126 : 0, t1 = half ? NT : 126;
        #pragma unroll 16
        for (int t = t0; t < t1; ++t) {
            float xv = xrow[t];
            qc = fmaf(qeC[t], xv, qc);
            kc = fmaf(keC[t], xv, kc);
        }
        p0[tid] = qc; p1[tid] = kc;
        __syncthreads();
        if (tid < 256) {
            qc = p0[tid] + p0[tid+256] + cst[0];
            kc = p1[tid] + p1[tid+256] + cst[1];
            kv[tid] = kc;
        }
        __syncthreads();
        if (tid < 256) {
            float s = cst[6];
            float qi = s * qc;
            float m0=-1e30f, m1=-1e30f, m2=-1e30f, m3=-1e30f;
            #pragma unroll 2
            for (int jj = 0; jj < NC; jj += 4) {
                m0 = fmaxf(m0, qi*kv[jj]);
                m1 = fmaxf(m1, qi*kv[jj+1]);
                m2 = fmaxf(m2, qi*kv[jj+2]);
                m3 = fmaxf(m3, qi*kv[jj+3]);
            }
            float m = fmaxf(fmaxf(m0,m1), fmaxf(m2,m3));
            float d0=0.f, d1=0.f, d2=0.f, d3=0.f;
            #pragma unroll 2
            for (int jj = 0; jj < NC; jj += 4) {
                d0 += __expf(qi*kv[jj]   - m);
                d1 += __expf(qi*kv[jj+1] - m);
                d2 += __expf(qi*kv[jj+2] - m);
                d3 += __expf(qi*kv[jj+3] - m);
            }
            float den = (d0+d1)+(d2+d3);
            atomicAdd(&ws[OFF_DC + tid], __expf(qi*kv[tid] - m)/den);
        }
    } else {
        float qf=0.f, kf=0.f, qt=0.f, kt=0.f;
        if (lid < NT) {
            const float* xc = xb + lid + (size_t)(half*128)*NSP;
            const float* qeF = ws + OFF_QEF + half*128;  const float* keF = ws + OFF_KEF + half*128;
            const float* qeT = ws + OFF_QET + half*128;  const float* keT = ws + OFF_KET + half*128;
            #pragma unroll 8
            for (int ch = 0; ch < 128; ++ch) {
                float xv = xc[(size_t)ch*NSP];
                qf = fmaf(qeF[ch], xv, qf);
                kf = fmaf(keF[ch], xv, kf);
                qt = fmaf(qeT[ch], xv, qt);
                kt = fmaf(keT[ch], xv, kt);
            }
        }
        p0[tid]=qf; p1[tid]=kf; p2[tid]=qt; p3[tid]=kt;
        __syncthreads();
        float qfv=0.f, kfv=0.f;
        if (tid < NT) {
            qfv = p0[tid] + p0[tid+256] + cst[2];
            kfv = p1[tid] + p1[tid+256] + cst[3];
            float qtv = p2[tid] + p2[tid+256] + cst[4];
            float ktv = p3[tid] + p3[tid+256] + cst[5];
            kv[tid] = kfv;
            if (fuse_t) {
                ws[OFF_QT + ((size_t)b*NT + tid)*NF + f] = qtv;
                ws[OFF_KT + ((size_t)b*NT + tid)*NF + f] = ktv;
            }
        }
        __syncthreads();
        if (tid < NT) {
            float s = cst[7];
            float qi = s * qfv;
            float m0=-1e30f, m1=-1e30f, m2=-1e30f, m3=-1e30f;
            int jj = 0;
            #pragma unroll 2
            for (; jj + 3 < NT; jj += 4) {
                m0 = fmaxf(m0, qi*kv[jj]);
                m1 = fmaxf(m1, qi*kv[jj+1]);
                m2 = fmaxf(m2, qi*kv[jj+2]);
                m3 = fmaxf(m3, qi*kv[jj+3]);
            }
            for (; jj < NT; ++jj) m0 = fmaxf(m0, qi*kv[jj]);
            float m = fmaxf(fmaxf(m0,m1), fmaxf(m2,m3));
            float d0=0.f, d1=0.f, d2=0.f, d3=0.f;
            jj = 0;
            #pragma unroll 2
            for (; jj + 3 < NT; jj += 4) {
                d0 += __expf(qi*kv[jj]   - m);
                d1 += __expf(qi*kv[jj+1] - m);
                d2 += __expf(qi*kv[jj+2] - m);
                d3 += __expf(qi*kv[jj+3] - m);
            }
            for (; jj < NT; ++jj) d0 += __expf(qi*kv[jj] - m);
            float den = (d0+d1)+(d2+d3);
            atomicAdd(&ws[OFF_DF + tid], __expf(qi*kfv - m)/den);
        }
    }
}

__global__ __launch_bounds__(256) void tsm_kernel(float* __restrict__ ws)
{
    __shared__ float dt_acc[NF];
    int tid = threadIdx.x, b = blockIdx.x;
    if (tid < NF) dt_acc[tid] = 0.f;
    __syncthreads();
    if (tid < NT) {
        float s = ws[OFF_CONST+8];
        const float* qp = ws + OFF_QT + ((size_t)b*NT + tid)*NF;
        const float* kp = ws + OFF_KT + ((size_t)b*NT + tid)*NF;
        float q[NF], k[NF];
        #pragma unroll
        for (int i = 0; i < NF; ++i) { q[i] = qp[i]; k[i] = kp[i]; }
        #pragma unroll
        for (int i = 0; i < NF; ++i) {
            float qi = s * q[i];
            float m = -1e30f;
            #pragma unroll
            for (int j = 0; j < NF; ++j) m = fmaxf(m, qi*k[j]);
            float den = 0.f;
            #pragma unroll
            for (int j = 0; j < NF; ++j) den += __expf(qi*k[j] - m);
            atomicAdd(&dt_acc[i], __expf(qi*k[i] - m)/den);
        }
    }
    __syncthreads();
    if (tid < NF) atomicAdd(&ws[OFF_DT + tid], dt_acc[tid]);
}

__global__ __launch_bounds__(256) void t_kernel(const float* __restrict__ x, float* __restrict__ ws)
{
    __shared__ float qs[32*NF], ks[32*NF], dt_acc[NF];
    int tid = threadIdx.x;
    int b  = blockIdx.x >> 3;
    int t0 = (blockIdx.x & 7) * 32;
    int tl = tid & 31, fr = tid >> 5;
    int t = t0 + tl;
    bool act = (fr < NF) && (t < NT);
    if (tid < NF) dt_acc[tid] = 0.f;

    float aq = 0.f, ak = 0.f;
    const float* qeT = ws + OFF_QET;
    const float* keT = ws + OFF_KET;
    if (act) {
        const float* xr = x + (size_t)b*NC*NSP + fr*NT + t;
        #pragma unroll 8
        for (int ch = 0; ch < NC; ++ch) {
            float xv = xr[(size_t)ch*NSP];
            aq = fmaf(qeT[ch], xv, aq);
            ak = fmaf(keT[ch], xv, ak);
        }
    }
    __syncthreads();
    if (act) {
        qs[tl*NF + fr] = aq + ws[OFF_CONST+4];
        ks[tl*NF + fr] = ak + ws[OFF_CONST+5];
    }
    __syncthreads();
    if (act) {
        float s = ws[OFF_CONST+8];
        float qi = s * qs[tl*NF + fr];
        float m = -1e30f;
        #pragma unroll
        for (int j = 0; j < NF; ++j) m = fmaxf(m, qi*ks[tl*NF + j]);
        float den = 0.f;
        #pragma unroll
        for (int j = 0; j < NF; ++j) den += __expf(qi*ks[tl*NF + j] - m);
        atomicAdd(&dt_acc[fr], __expf(qi*ks[tl*NF + fr] - m)/den);
    }
    __syncthreads();
    if (tid < NF) atomicAdd(&ws[OFF_DT + tid], dt_acc[tid]);
}

// --------------------- main2: MFMA straight from global bf16 images,
// register-double-buffered prefetch (fully unrolled -> static slot indices).
__global__ __launch_bounds__(256, 3) void main2_kernel(
    const float* __restrict__ x, const float* __restrict__ ws, float* __restrict__ out)
{
    __shared__ float vsL[128], voL[128], dcL[128], dtfL[128];
    int tid = threadIdx.x;
    int flat = blockIdx.x;                 // 0..895
    int xcd = flat & 7, idx = flat >> 3;   // idx 0..111
    int pair = xcd*56 + (idx >> 1);        // 0..447
    int o0 = (idx & 1) * 128;
    int n0 = (pair % 14) * 128;
    int b  = pair / 14;
    const size_t xbase = (size_t)b * NC * NSP;

    // epilogue scalars: issue loads early, write LDS after K-loop
    float evs=0.f, evo=0.f, edc=0.f, edtf=0.f;
    if (tid < 128) {
        int o = o0 + tid;
        evs = ws[OFF_VSC+o];
        evo = ws[OFF_VOF+o];
        edc = ws[OFF_DC+o];
        int nn = n0 + tid; if (nn > NSP-1) nn = NSP-1;
        int ff = nn / NT, tt = nn - ff*NT;
        edtf = ws[OFF_DT+ff] + ws[OFF_DF+tt];
    }

    int wv = tid >> 6, ln = tid & 63;
    int quad = ln >> 4, l16 = ln & 15;
    int wr = wv >> 1, wc = wv & 1;

    const u16* wimg = (const u16*)(ws + OFF_WB16) + (size_t)(o0 >> 7) * 32768;
    const unsigned int* ximg = (const unsigned int*)(ws + OFF_XB16)
                             + (size_t)(b*14 + (n0 >> 7)) * 16384;

    float4v acc[4][4] = {};
    short8 afr[2][4];
    int2v blo[2][4], bhi[2][4];

    auto LF = [&](int ks, int s) {
        #pragma unroll
        for (int fr = 0; fr < 4; ++fr)
            afr[s][fr] = *(const short8*)&wimg[ks*4096 + (wr*4+fr)*512 + ln*8];
        #pragma unroll
        for (int fc = 0; fc < 4; ++fc) {
            int nn = wc*64 + fc*16 + l16;
            blo[s][fc] = *(const int2v*)&ximg[ks*2048 + (2*quad)*256 + 2*nn];
            bhi[s][fc] = *(const int2v*)&ximg[ks*2048 + (2*quad+1)*256 + 2*nn];
        }
    };

    LF(0, 0);
    #pragma unroll
    for (int ks = 0; ks < 8; ++ks) {
        const int cur = ks & 1;
        if (ks < 7) LF(ks+1, cur ^ 1);     // next-step loads in flight over MFMAs
        #pragma unroll
        for (int fc = 0; fc < 4; ++fc) {
            union { int i4[4]; short8 v; } u;
            u.i4[0] = blo[cur][fc].x; u.i4[1] = blo[cur][fc].y;
            u.i4[2] = bhi[cur][fc].x; u.i4[3] = bhi[cur][fc].y;
            short8 bv = u.v;
            #pragma unroll
            for (int fr = 0; fr < 4; ++fr)
                acc[fr][fc] = __builtin_amdgcn_mfma_f32_16x16x32_bf16(
                    afr[cur][fr], bv, acc[fr][fc], 0, 0, 0);
        }
    }

    if (tid < 128) { vsL[tid]=evs; voL[tid]=evo; dcL[tid]=edc; dtfL[tid]=edtf; }
    __syncthreads();

    #pragma unroll
    for (int fr = 0; fr < 4; ++fr) {
        #pragma unroll
        for (int r = 0; r < 4; ++r) {
            int ol = wr*64 + fr*16 + quad*4 + r;
            int o = o0 + ol;
            float vs = vsL[ol], vo = voL[ol], dcv = dcL[ol];
            const size_t orow = xbase + (size_t)o*NSP;
            #pragma unroll
            for (int fc = 0; fc < 4; ++fc) {
                int nl = wc*64 + fc*16 + l16;
                int nn = n0 + nl;
                if (nn < NSP) {
                    size_t gi = orow + nn;
                    out[gi] = (acc[fr][fc][r]*vs + vo)*(dcv + dtfL[nl]) + x[gi];
                }
            }
        }
    }
}

// --------------------- fallback main GEMM (LDS-staged, double-buffered)
template<int WBF>
__global__ __launch_bounds__(256) void main_kernel(
    const float* __restrict__ x, const float* __restrict__ vw,
    const float* __restrict__ ws, float* __restrict__ out)
{
    __shared__ u16 Ws[2][4096];
    __shared__ unsigned int Xs[2][2048];
    __shared__ float vsL[128], voL[128], dcL[128], dtfL[128];

    int tid = threadIdx.x;
    int flat = blockIdx.x;
    int xcd = flat & 7, idx = flat >> 3;
    int pair = xcd*56 + (idx >> 1);
    int o0 = (idx & 1) * 128;
    int n0 = (pair % 14) * 128;
    int b  = pair / 14;
    const size_t xbase = (size_t)b * NC * NSP;

    if (tid < 128) {
        int o = o0 + tid;
        vsL[tid] = ws[OFF_VSC+o];
        voL[tid] = ws[OFF_VOF+o];
        dcL[tid] = ws[OFF_DC+o];
        int nn = n0 + tid; if (nn > NSP-1) nn = NSP-1;
        int ff = nn / NT, tt = nn - ff*NT;
        dtfL[tid] = ws[OFF_DT+ff] + ws[OFF_DF+tt];
    }

    int wv = tid >> 6, ln = tid & 63;
    int quad = ln >> 4, l16 = ln & 15;
    int wr = wv >> 1, wc = wv & 1;

    float4v acc[4][4] = {};

    int kgs = tid >> 5, nbs = tid & 31;
    int oo = tid >> 1, half = tid & 1;

    const u16* wbg = nullptr;
    if constexpr (WBF) wbg = (const u16*)(ws + OFF_WB16) + (size_t)(o0 >> 7) * 32768;

    int4v wA, wB;
    float wf[16];
    float xv[4][4];

    auto loadW = [&](int ks) {
        if constexpr (WBF) {
            const int4v* wsrc = (const int4v*)(wbg + (size_t)ks*4096);
            wA = wsrc[tid]; wB = wsrc[256 + tid];
        } else {
            const float* wr4 = vw + (size_t)(o0+oo)*NC + ks*32 + half*16;
            #pragma unroll
            for (int c = 0; c < 16; ++c) wf[c] = wr4[c];
        }
    };
    auto loadX = [&](int ks) {
        int nbase = n0 + nbs*4;
        const float* xr = x + xbase + (size_t)(ks*32 + kgs*4)*NSP + nbase;
        if (nbase + 3 < NSP) {
            #pragma unroll
            for (int rr = 0; rr < 4; ++rr)
                #pragma unroll
                for (int i = 0; i < 4; ++i)
                    xv[rr][i] = xr[(size_t)rr*NSP + i];
        } else {
            #pragma unroll
            for (int rr = 0; rr < 4; ++rr)
                #pragma unroll
                for (int i = 0; i < 4; ++i)
                    xv[rr][i] = (nbase + i < NSP) ? xr[(size_t)rr*NSP + i] : 0.f;
        }
    };
    auto storeWX = [&](int bufi) {
        if constexpr (WBF) {
            *(int4v*)&Ws[bufi][tid*8]        = wA;
            *(int4v*)&Ws[bufi][2048 + tid*8] = wB;
        } else {
            union { u16 us[16]; short8 v[2]; } wb;
            #pragma unroll
            for (int c = 0; c < 16; ++c) wb.us[c] = f2b(wf[c]);
            int frg = oo >> 4, o16 = oo & 15;
            #pragma unroll
            for (int qq = 0; qq < 2; ++qq) {
                int qd = 2*half + qq;
                *(short8*)&Ws[bufi][frg*512 + qd*128 + o16*8] = wb.v[qq];
            }
        }
        unsigned int pk[8];
        #pragma unroll
        for (int i = 0; i < 4; ++i)
            #pragma unroll
            for (int jp = 0; jp < 2; ++jp)
                pk[i*2+jp] = pk2(xv[2*jp][i], xv[2*jp+1][i]);
        *(int4v*)&Xs[bufi][XSW(kgs, nbs*8)]     = *(int4v*)&pk[0];
        *(int4v*)&Xs[bufi][XSW(kgs, nbs*8 + 4)] = *(int4v*)&pk[4];
    };

    loadW(0); loadX(0);
    storeWX(0);
    __syncthreads();

    for (int ks = 0; ks < 8; ++ks) {
        int cur = ks & 1;
        if (ks < 7) { loadW(ks+1); loadX(ks+1); }

        short8 afr[4], bfr[4];
        #pragma unroll
        for (int fr = 0; fr < 4; ++fr)
            afr[fr] = *(short8*)&Ws[cur][(wr*4+fr)*512 + ln*8];
        #pragma unroll
        for (int fc = 0; fc < 4; ++fc) {
            int nn = wc*64 + fc*16 + l16;
            int2v lo = *(int2v*)&Xs[cur][XSW(2*quad,   2*nn)];
            int2v hi = *(int2v*)&Xs[cur][XSW(2*quad+1, 2*nn)];
            union { int i4[4]; short8 v; } u;
            u.i4[0] = lo.x; u.i4[1] = lo.y; u.i4[2] = hi.x; u.i4[3] = hi.y;
            bfr[fc] = u.v;
        }
        #pragma unroll
        for (int fr = 0; fr < 4; ++fr)
            #pragma unroll
            for (int fc = 0; fc < 4; ++fc)
                acc[fr][fc] = __builtin_amdgcn_mfma_f32_16x16x32_bf16(
                    afr[fr], bfr[fc], acc[fr][fc], 0, 0, 0);

        if (ks < 7) storeWX(cur ^ 1);
        __syncthreads();
    }

    #pragma unroll
    for (int fr = 0; fr < 4; ++fr) {
        #pragma unroll
        for (int r = 0; r < 4; ++r) {
            int ol = wr*64 + fr*16 + quad*4 + r;
            int o = o0 + ol;
            float vs = vsL[ol], vo = voL[ol], dcv = dcL[ol];
            const size_t orow = xbase + (size_t)o*NSP;
            #pragma unroll
            for (int fc = 0; fc < 4; ++fc) {
                int nl = wc*64 + fc*16 + l16;
                int nn = n0 + nl;
                if (nn < NSP) {
                    size_t gi = orow + nn;
                    out[gi] = (acc[fr][fc][r]*vs + vo)*(dcv + dtfL[nl]) + x[gi];
                }
            }
        }
    }
}

extern "C" void kernel_launch(void* const* d_in, const int* in_sizes, int n_in,
                              void* d_out, int out_size, void* d_ws, size_t ws_size,
                              hipStream_t stream)
{
    const float* x    = (const float*)d_in[0];
    const float* qc_w = (const float*)d_in[1];  const float* qc_bn = (const float*)d_in[2];
    const float* kc_w = (const float*)d_in[3];  const float* kc_bn = (const float*)d_in[4];
    const float* lc_bn= (const float*)d_in[5];
    const float* qf_w = (const float*)d_in[6];  const float* qf_bn = (const float*)d_in[7];
    const float* kf_w = (const float*)d_in[8];  const float* kf_bn = (const float*)d_in[9];
    const float* lf_bn= (const float*)d_in[10];
    const float* qt_w = (const float*)d_in[11]; const float* qt_bn = (const float*)d_in[12];
    const float* kt_w = (const float*)d_in[13]; const float* kt_bn = (const float*)d_in[14];
    const float* lt_bn= (const float*)d_in[15];
    const float* v_w  = (const float*)d_in[16]; const float* v_b   = (const float*)d_in[17];
    const float* v_bn = (const float*)d_in[18];
    float* ws = (float*)d_ws;
    float* out = (float*)d_out;

    int fuse_t = (ws_size >= (size_t)WS2_END * sizeof(float)) ? 1 : 0;
    int wbf    = (ws_size >= (size_t)WS3_END * sizeof(float)) ? 1 : 0;
    int newq   = (ws_size >= (size_t)WS4_END * sizeof(float)) ? 1 : 0;
    int xb     = (ws_size >= (size_t)WS5_END * sizeof(float)) ? 1 : 0;

    prep_kernel<<<wbf ? 33 : 25, 256, 0, stream>>>(qc_w,qc_bn,kc_w,kc_bn,lc_bn,
                                                   qf_w,qf_bn,kf_w,kf_bn,lf_bn,
                                                   qt_w,qt_bn,kt_w,kt_bn,lt_bn,
                                                   v_b,v_bn,v_w,ws);
    if (newq) {
        qv_kernel<<<2240, 512, 0, stream>>>(x, ws, xb);
        sm_kernel<<<256, 256, 0, stream>>>(ws);
    } else {
        qkt_kernel<<<NB*NF*2, 512, 0, stream>>>(x, ws, fuse_t);
        if (fuse_t) tsm_kernel<<<NB, 256, 0, stream>>>(ws);
        else        t_kernel<<<NB*8, 256, 0, stream>>>(x, ws);
    }
    if (xb && wbf)
        main2_kernel<<<896, 256, 0, stream>>>(x, ws, out);
    else if (wbf)
        main_kernel<1><<<896, 256, 0, stream>>>(x, v_w, ws, out);
    else
        main_kernel<0><<<896, 256, 0, stream>>>(x, v_w, ws, out);
}

// Round 6
// 215.202 us; speedup vs baseline: 1.0490x; 1.0490x over previous
//
#include <hip/hip_runtime.h>

typedef unsigned short u16;
typedef __attribute__((ext_vector_type(8))) short short8;
typedef __attribute__((ext_vector_type(4))) float float4v;
typedef __attribute__((ext_vector_type(4))) int int4v;
typedef __attribute__((ext_vector_type(2))) int int2v;

#define EPS 1e-5f
#define NC 256
#define NT 251
#define NF 7
#define NSP 1757   // NF*NT
#define NB 32

// workspace layout (float offsets)
#define OFF_QEC 0
#define OFF_KEC 256
#define OFF_QEF 512
#define OFF_KEF 768
#define OFF_QET 1024
#define OFF_KET 1280
#define OFF_VSC 1536
#define OFF_VOF 1792
#define OFF_CONST 2048   // [0..5]=q/k consts c,f,t  [6]=s_c [7]=s_f [8]=s_t
#define OFF_DC 2064      // 256
#define OFF_DF 2320      // 256 (251 used)
#define OFF_DT 2576      // 16 (7 used)
#define WS_END 2592
// fused-t staging (old layout [b][t][f] for fallback; new path uses [b][sp])
#define OFF_QT 2592            // 56320
#define OFF_KT (OFF_QT+56320)  // 56320
#define WS2_END (OFF_KT+56320) // 115232 floats
// pre-tiled bf16 v_w in MFMA LDS layout
#define OFF_WB16 WS2_END
#define WS3_END (WS2_END+32768) // 148000 floats
// new-path staging: qf/kf [b][sp], qc/kc [n][ch]
#define OFF_QF2 WS3_END              // 56320
#define OFF_KF2 (OFF_QF2+56320)      // 56320
#define OFF_QCS (OFF_KF2+56320)      // 57344
#define OFF_KCS (OFF_QCS+57344)      // 57344
#define WS4_END (OFF_KCS+57344)      // 375328 floats ≈ 1.43 MB
// bf16 x image in main's B-fragment order: [b][nchunk14][ks8][kg8][w256] u32
#define OFF_XB16 WS4_END
#define XB16_U32 (448*16384)         // 7340032 u32
#define WS5_END (OFF_XB16 + XB16_U32) // 7715360 floats ≈ 29.4 MB

// Xs swizzle for fallback main_kernel LDS (4-way -> 2-way on b64 frag reads)
#define XSW(kg, w) ((kg)*256 + ((w) ^ ((((kg)>>1)&3)<<3)))

__device__ __forceinline__ u16 f2b(float f) {   // fp32 -> bf16 RNE
    unsigned int u = __float_as_uint(f);
    return (u16)((u + 0x7FFFu + ((u >> 16) & 1u)) >> 16);
}
__device__ __forceinline__ unsigned int pk2(float a, float b) {
    return (unsigned int)f2b(a) | ((unsigned int)f2b(b) << 16);
}

// ---------------------------------------------------------------- prep
// blocks 0..23: matvecs; 24: scalars+zero small; 25..32: WB16 tiling (wbf);
// 33..36: zero QF2/KF2/QT/KT for the atomic qv path (nz)
__global__ __launch_bounds__(256) void prep_kernel(
    const float* qc_w, const float* qc_bn, const float* kc_w, const float* kc_bn, const float* lc_bn,
    const float* qf_w, const float* qf_bn, const float* kf_w, const float* kf_bn, const float* lf_bn,
    const float* qt_w, const float* qt_bn, const float* kt_w, const float* kt_bn, const float* lt_bn,
    const float* v_b, const float* v_bn, const float* v_w, float* ws, int nz)
{
    int tid = threadIdx.x;
    int blk = blockIdx.x;
    __shared__ float sc[256];
    __shared__ float red[256];
    if (blk < 24) {
        int m = blk >> 2, j = blk & 3;
        const float* w; const float* bn; float* out; int O;
        switch (m) {
            case 0: w=qc_w; bn=qc_bn; out=ws+OFF_QEC; O=NT; break;
            case 1: w=kc_w; bn=kc_bn; out=ws+OFF_KEC; O=NT; break;
            case 2: w=qf_w; bn=qf_bn; out=ws+OFF_QEF; O=NC; break;
            case 3: w=kf_w; bn=kf_bn; out=ws+OFF_KEF; O=NC; break;
            case 4: w=qt_w; bn=qt_bn; out=ws+OFF_QET; O=NC; break;
            default: w=kt_w; bn=kt_bn; out=ws+OFF_KET; O=NC; break;
        }
        if (tid < O) sc[tid] = bn[tid] * rsqrtf(bn[3*O+tid] + EPS);
        __syncthreads();
        int tl = tid & 63, kc4 = tid >> 6;
        int t = j*64 + tl;
        float acc = 0.f;
        if (t < O) {
            #pragma unroll 8
            for (int o = kc4; o < O; o += 4)
                acc = fmaf(sc[o], w[(size_t)o*O + t], acc);
        }
        red[tid] = acc;
        __syncthreads();
        if (tid < 64) {
            int tt = j*64 + tid;
            if (tt < O)
                out[tt] = (red[tid] + red[tid+64] + red[tid+128] + red[tid+192]) / (float)O;
        }
        if (j == 0) {
            float bs = 0.f;
            if (tid < O) bs = bn[O+tid] - bn[2*O+tid]*sc[tid];
            __syncthreads();
            red[tid] = bs; __syncthreads();
            for (int s2 = 128; s2 > 0; s2 >>= 1) { if (tid < s2) red[tid] += red[tid+s2]; __syncthreads(); }
            if (tid == 0) ws[OFF_CONST+m] = red[0] / (float)O;
        }
    } else if (blk == 24) {
        if (tid < NC) {
            float s = v_bn[tid] * rsqrtf(v_bn[3*NC+tid] + EPS);
            ws[OFF_VSC+tid] = s;
            ws[OFF_VOF+tid] = v_bn[NC+tid] - v_bn[2*NC+tid]*s + v_b[tid]*s;
        }
        if (tid == 0) {
            ws[OFF_CONST+6] = lc_bn[0] * rsqrtf(lc_bn[3] + EPS);
            ws[OFF_CONST+7] = lf_bn[0] * rsqrtf(lf_bn[3] + EPS);
            ws[OFF_CONST+8] = lt_bn[0] * rsqrtf(lt_bn[3] + EPS);
        }
        for (int i = tid; i < WS_END - OFF_DC; i += 256) ws[OFF_DC + i] = 0.f;
    } else if (blk < 33) {
        // blocks 25..32: tile v_w -> bf16 MFMA layout. Coalesced float4 reads,
        // scattered 8B writes.
        u16* wb = (u16*)(ws + OFF_WB16);
        int base = (blk - 25) * 8192;   // elements of v_w
        for (int i4 = tid; i4 < 2048; i4 += 256) {
            int e = base + i4*4;
            int o = e >> 8, k = e & 255;
            float4v v = *(const float4v*)(v_w + e);
            u16 h0 = f2b(v.x), h1 = f2b(v.y), h2 = f2b(v.z), h3 = f2b(v.w);
            int r = ((o>>7)<<3) | (k>>5);
            int q = (((o>>4)&7)<<9) | (((k>>3)&3)<<7) | ((o&15)<<3) | (k&7);
            unsigned long long pk = (unsigned long long)h0 | ((unsigned long long)h1<<16)
                                  | ((unsigned long long)h2<<32) | ((unsigned long long)h3<<48);
            *(unsigned long long*)&wb[(r<<12) | q] = pk;
        }
    } else {
        // blocks 33..36: zero the atomic accumulators (only in newq mode)
        if (!nz) return;
        int z = blk - 33;
        float* p;
        switch (z) {
            case 0: p = ws + OFF_QF2; break;
            case 1: p = ws + OFF_KF2; break;
            case 2: p = ws + OFF_QT;  break;
            default: p = ws + OFF_KT; break;
        }
        float4v zv = {0.f, 0.f, 0.f, 0.f};
        for (int i = tid; i < 14080; i += 256) ((float4v*)p)[i] = zv;
    }
}

// --------------- qv/kv computation, single pass structure, staged to ws
// blocks 0..895   : ft-part, (pair, ch-half). 128 ch x 128 sp per block.
//                   atomicAdd partials -> QF2/KF2/QT/KT (consts added in sm).
//                   also emits the bf16 x-image (its ch-half) if pack.
// blocks 896..4479: c-part, (n, 16ch-tile) -> QCS/KCS (raw, consts in sm).
__global__ __launch_bounds__(512) void qv_kernel(const float* __restrict__ x,
                                                 float* __restrict__ ws, int pack)
{
    __shared__ float lds[6144];
    int tid = threadIdx.x;
    int blk = blockIdx.x;

    if (blk < 896) {
        // ---------- ft-part ----------
        int half = blk & 1;
        int pairid = blk >> 1;           // 0..447
        int b = pairid / 14, nchunk = pairid % 14;
        int n0 = nchunk * 128;
        int spg = tid & 31, chg = tid >> 5;   // 16 chg-groups x 8 ch each (this half)
        // stage this half's e-vectors: [qf 4096][kf 4224][qt 4352][kt 4480], 128 each
        if (tid < 128) {
            lds[4096+tid] = ws[OFF_QEF + half*128 + tid];
            lds[4352+tid] = ws[OFF_QET + half*128 + tid];
        } else if (tid < 256) {
            int u = tid - 128;
            lds[4224+u] = ws[OFF_KEF + half*128 + u];
            lds[4480+u] = ws[OFF_KET + half*128 + u];
        }
        __syncthreads();
        const size_t xbase = (size_t)b*NC*NSP;
        int sp0 = n0 + spg*4;
        bool full = (sp0 + 3 < NSP);
        unsigned int* ximg = nullptr;
        if (pack) ximg = (unsigned int*)(ws + OFF_XB16) + (size_t)(b*14 + nchunk)*16384;

        float qf[4]={0,0,0,0}, kf[4]={0,0,0,0}, qt[4]={0,0,0,0}, kt[4]={0,0,0,0};
        #pragma unroll
        for (int ii = 0; ii < 2; ++ii) {
            int chl0 = chg*8 + ii*4;          // local ch base 0..124
            int ch0 = half*128 + chl0;        // global ch base
            float xv4[4][4];
            #pragma unroll
            for (int cc = 0; cc < 4; ++cc) {
                int ch = ch0 + cc;
                const float* xr = x + xbase + (size_t)ch*NSP + sp0;
                if (full) {
                    xv4[cc][0]=xr[0]; xv4[cc][1]=xr[1]; xv4[cc][2]=xr[2]; xv4[cc][3]=xr[3];
                } else {
                    #pragma unroll
                    for (int j = 0; j < 4; ++j) xv4[cc][j] = (sp0+j < NSP) ? xr[j] : 0.f;
                }
                float eqf = lds[4096+chl0+cc], ekf = lds[4224+chl0+cc];
                float eqt = lds[4352+chl0+cc], ekt = lds[4480+chl0+cc];
                #pragma unroll
                for (int j = 0; j < 4; ++j) {
                    qf[j] = fmaf(eqf, xv4[cc][j], qf[j]);
                    kf[j] = fmaf(ekf, xv4[cc][j], kf[j]);
                    qt[j] = fmaf(eqt, xv4[cc][j], qt[j]);
                    kt[j] = fmaf(ekt, xv4[cc][j], kt[j]);
                }
            }
            if (pack) {
                int kgsg = ch0 >> 2;          // half*32 + chg*2 + ii  (0..63)
                int ks = kgsg >> 3, kgl = kgsg & 7;
                unsigned int* dst = ximg + ks*2048 + kgl*256 + spg*8;
                unsigned int pk[8];
                #pragma unroll
                for (int i = 0; i < 4; ++i) {
                    pk[i*2+0] = pk2(xv4[0][i], xv4[1][i]);
                    pk[i*2+1] = pk2(xv4[2][i], xv4[3][i]);
                }
                *(int4v*)&dst[0] = *(int4v*)&pk[0];
                *(int4v*)&dst[4] = *(int4v*)&pk[4];
            }
        }
        // fold chg-pairs across wave halves (lanes 0-31 <-> 32-63)
        #pragma unroll
        for (int j = 0; j < 4; ++j) {
            qf[j] += __shfl_xor(qf[j], 32);
            kf[j] += __shfl_xor(kf[j], 32);
            qt[j] += __shfl_xor(qt[j], 32);
            kt[j] += __shfl_xor(kt[j], 32);
        }
        int wv = tid >> 6, ln = tid & 63;
        if (ln < 32) {
            // [v(16)][wv(8)][spg(32)]: bank = spg -> conflict-free
            #pragma unroll
            for (int j = 0; j < 4; ++j) {
                lds[(j)*256     + wv*32 + ln] = qf[j];
                lds[(4+j)*256   + wv*32 + ln] = kf[j];
                lds[(8+j)*256   + wv*32 + ln] = qt[j];
                lds[(12+j)*256  + wv*32 + ln] = kt[j];
            }
        }
        __syncthreads();
        if (tid < 32) {
            float acc[16];
            #pragma unroll
            for (int v = 0; v < 16; ++v) {
                float s = 0.f;
                #pragma unroll
                for (int w = 0; w < 8; ++w) s += lds[v*256 + w*32 + tid];
                acc[v] = s;
            }
            int sp0w = n0 + tid*4;
            #pragma unroll
            for (int j = 0; j < 4; ++j) {
                if (sp0w + j < NSP) {
                    size_t o = (size_t)b*1760 + sp0w + j;
                    atomicAdd(&ws[OFF_QF2 + o], acc[j]);
                    atomicAdd(&ws[OFF_KF2 + o], acc[4+j]);
                    atomicAdd(&ws[OFF_QT  + o], acc[8+j]);
                    atomicAdd(&ws[OFF_KT  + o], acc[12+j]);
                }
            }
        }
    } else {
        // ---------- c-part: 16-row tiles ----------
        int blk2 = blk - 896;            // 0..3583
        int n = blk2 >> 4, cb = blk2 & 15;
        int b = n / NF, f = n % NF;
        const float* xb = x + (size_t)b*NC*NSP + (size_t)f*NT + (size_t)(cb*16)*NSP;
        // qe at 4112, ke at 4368; tile [16][257] at 0; pq 4624, pk 5136
        if (tid < NT) lds[4112+tid] = ws[OFF_QEC+tid];
        else if (tid >= 256 && tid < 256+NT) lds[4368+tid-256] = ws[OFF_KEC+tid-256];
        int lr = tid >> 8, lane = tid & 255;
        #pragma unroll
        for (int i = 0; i < 8; ++i) {     // full unroll: 8 loads in flight
            int r = 2*i + lr;
            if (lane < NT) lds[r*257 + lane] = xb[(size_t)r*NSP + lane];
        }
        __syncthreads();
        int r = tid & 15, seg = tid >> 4;  // 16 r x 32 seg (8 t each)
        int t0 = seg*8, t1 = (seg == 31) ? NT : t0+8;
        float qa = 0.f, ka = 0.f;
        #pragma unroll 8
        for (int t = t0; t < t1; ++t) {
            float xv = lds[r*257 + t];
            qa = fmaf(lds[4112+t], xv, qa);
            ka = fmaf(lds[4368+t], xv, ka);
        }
        lds[4624 + seg*16 + r] = qa;      // addr = tid: conflict-free
        lds[5136 + seg*16 + r] = ka;
        __syncthreads();
        if (tid < 32) {
            int rr = tid & 15, which = tid >> 4;
            int base = (which ? 5136 : 4624) + rr;
            float s = 0.f;
            #pragma unroll
            for (int sg = 0; sg < 32; ++sg) s += lds[base + sg*16];
            int ch = cb*16 + rr;
            if (which == 0) ws[OFF_QCS + n*256 + ch] = s;
            else            ws[OFF_KCS + n*256 + ch] = s;
        }
    }
}

// --------------- all three diag softmaxes from staged q/k (adds consts)
__global__ __launch_bounds__(256) void sm_kernel(float* __restrict__ ws)
{
    __shared__ float kv[NC];
    __shared__ float kv2[NT];
    __shared__ float dt_acc[NF];
    int tid = threadIdx.x, blk = blockIdx.x;
    const float* cst = ws + OFF_CONST;

    if (blk < 224) {
        int b = blk / NF, f = blk % NF;
        float qcv = ws[OFF_QCS + blk*256 + tid] + cst[0];
        float kcv = ws[OFF_KCS + blk*256 + tid] + cst[1];
        kv[tid] = kcv;
        float qfv = 0.f, kfv = 0.f;
        if (tid < NT) {
            size_t o = (size_t)b*1760 + f*NT + tid;
            qfv = ws[OFF_QF2 + o] + cst[2];
            kfv = ws[OFF_KF2 + o] + cst[3];
            kv2[tid] = kfv;
        }
        __syncthreads();
        {   // c diag softmax
            float s = cst[6];
            float qi = s * qcv;
            float m0=-1e30f, m1=-1e30f, m2=-1e30f, m3=-1e30f;
            #pragma unroll 2
            for (int jj = 0; jj < NC; jj += 4) {
                m0 = fmaxf(m0, qi*kv[jj]);
                m1 = fmaxf(m1, qi*kv[jj+1]);
                m2 = fmaxf(m2, qi*kv[jj+2]);
                m3 = fmaxf(m3, qi*kv[jj+3]);
            }
            float m = fmaxf(fmaxf(m0,m1), fmaxf(m2,m3));
            float d0=0.f, d1=0.f, d2=0.f, d3=0.f;
            #pragma unroll 2
            for (int jj = 0; jj < NC; jj += 4) {
                d0 += __expf(qi*kv[jj]   - m);
                d1 += __expf(qi*kv[jj+1] - m);
                d2 += __expf(qi*kv[jj+2] - m);
                d3 += __expf(qi*kv[jj+3] - m);
            }
            float den = (d0+d1)+(d2+d3);
            atomicAdd(&ws[OFF_DC + tid], __expf(qi*kcv - m)/den);
        }
        if (tid < NT) {   // f diag softmax
            float s = cst[7];
            float qi = s * qfv;
            float m0=-1e30f, m1=-1e30f, m2=-1e30f, m3=-1e30f;
            int jj = 0;
            #pragma unroll 2
            for (; jj + 3 < NT; jj += 4) {
                m0 = fmaxf(m0, qi*kv2[jj]);
                m1 = fmaxf(m1, qi*kv2[jj+1]);
                m2 = fmaxf(m2, qi*kv2[jj+2]);
                m3 = fmaxf(m3, qi*kv2[jj+3]);
            }
            for (; jj < NT; ++jj) m0 = fmaxf(m0, qi*kv2[jj]);
            float m = fmaxf(fmaxf(m0,m1), fmaxf(m2,m3));
            float d0=0.f, d1=0.f, d2=0.f, d3=0.f;
            jj = 0;
            #pragma unroll 2
            for (; jj + 3 < NT; jj += 4) {
                d0 += __expf(qi*kv2[jj]   - m);
                d1 += __expf(qi*kv2[jj+1] - m);
                d2 += __expf(qi*kv2[jj+2] - m);
                d3 += __expf(qi*kv2[jj+3] - m);
            }
            for (; jj < NT; ++jj) d0 += __expf(qi*kv2[jj] - m);
            float den = (d0+d1)+(d2+d3);
            atomicAdd(&ws[OFF_DF + tid], __expf(qi*kfv - m)/den);
        }
    } else {
        int b = blk - 224;
        if (tid < NF) dt_acc[tid] = 0.f;
        __syncthreads();
        if (tid < NT) {
            float s = cst[8];
            float q[NF], k[NF];
            #pragma unroll
            for (int i = 0; i < NF; ++i) {
                size_t o = (size_t)b*1760 + i*NT + tid;
                q[i] = ws[OFF_QT + o] + cst[4];
                k[i] = ws[OFF_KT + o] + cst[5];
            }
            #pragma unroll
            for (int i = 0; i < NF; ++i) {
                float qi = s * q[i];
                float m = -1e30f;
                #pragma unroll
                for (int j = 0; j < NF; ++j) m = fmaxf(m, qi*k[j]);
                float den = 0.f;
                #pragma unroll
                for (int j = 0; j < NF; ++j) den += __expf(qi*k[j] - m);
                atomicAdd(&dt_acc[i], __expf(qi*k[i] - m)/den);
            }
        }
        __syncthreads();
        if (tid < NF) atomicAdd(&ws[OFF_DT + tid], dt_acc[tid]);
    }
}

// ------------ OLD-PATH kernels (fallback when ws too small) ------------
__global__ __launch_bounds__(512) void qkt_kernel(const float* __restrict__ x,
                                                  float* __restrict__ ws, int fuse_t)
{
    __shared__ float kv[NC];
    __shared__ float p0[512], p1[512], p2[512], p3[512];
    int tid = threadIdx.x;
    int bid = blockIdx.x;
    int n = bid >> 1, role = bid & 1;
    int b = n / NF, f = n % NF;
    const float* xb = x + (size_t)b*NC*NSP + (size_t)f*NT;
    const float* cst = ws + OFF_CONST;
    int half = tid >> 8, lid = tid & 255;

    if (role == 0) {
        const float* xrow = xb + (size_t)lid*NSP;
        const float* qeC = ws + OFF_QEC;  const float* keC = ws + OFF_KEC;
        float qc = 0.f, kc = 0.f;
        int t0 = half ? 126 : 0, t1 = half ? NT : 126;
        #pragma unroll 16
        for (int t = t0; t < t1; ++t) {
            float xv = xrow[t];
            qc = fmaf(qeC[t], xv, qc);
            kc = fmaf(keC[t], xv, kc);
        }
        p0[tid] = qc; p1[tid] = kc;
        __syncthreads();
        if (tid < 256) {
            qc = p0[tid] + p0[tid+256] + cst[0];
            kc = p1[tid] + p1[tid+256] + cst[1];
            kv[tid] = kc;
        }
        __syncthreads();
        if (tid < 256) {
            float s = cst[6];
            float qi = s * qc;
            float m0=-1e30f, m1=-1e30f, m2=-1e30f, m3=-1e30f;
            #pragma unroll 2
            for (int jj = 0; jj < NC; jj += 4) {
                m0 = fmaxf(m0, qi*kv[jj]);
                m1 = fmaxf(m1, qi*kv[jj+1]);
                m2 = fmaxf(m2, qi*kv[jj+2]);
                m3 = fmaxf(m3, qi*kv[jj+3]);
            }
            float m = fmaxf(fmaxf(m0,m1), fmaxf(m2,m3));
            float d0=0.f, d1=0.f, d2=0.f, d3=0.f;
            #pragma unroll 2
            for (int jj = 0; jj < NC; jj += 4) {
                d0 += __expf(qi*kv[jj]   - m);
                d1 += __expf(qi*kv[jj+1] - m);
                d2 += __expf(qi*kv[jj+2] - m);
                d3 += __expf(qi*kv[jj+3] - m);
            }
            float den = (d0+d1)+(d2+d3);
            atomicAdd(&ws[OFF_DC + tid], __expf(qi*kv[tid] - m)/den);
        }
    } else {
        float qf=0.f, kf=0.f, qt=0.f, kt=0.f;
        if (lid < NT) {
            const float* xc = xb + lid + (size_t)(half*128)*NSP;
            const float* qeF = ws + OFF_QEF + half*128;  const float* keF = ws + OFF_KEF + half*128;
            const float* qeT = ws + OFF_QET + half*128;  const float* keT = ws + OFF_KET + half*128;
            #pragma unroll 8
            for (int ch = 0; ch < 128; ++ch) {
                float xv = xc[(size_t)ch*NSP];
                qf = fmaf(qeF[ch], xv, qf);
                kf = fmaf(keF[ch], xv, kf);
                qt = fmaf(qeT[ch], xv, qt);
                kt = fmaf(keT[ch], xv, kt);
            }
        }
        p0[tid]=qf; p1[tid]=kf; p2[tid]=qt; p3[tid]=kt;
        __syncthreads();
        float qfv=0.f, kfv=0.f;
        if (tid < NT) {
            qfv = p0[tid] + p0[tid+256] + cst[2];
            kfv = p1[tid] + p1[tid+256] + cst[3];
            float qtv = p2[tid] + p2[tid+256] + cst[4];
            float ktv = p3[tid] + p3[tid+256] + cst[5];
            kv[tid] = kfv;
            if (fuse_t) {
                ws[OFF_QT + ((size_t)b*NT + tid)*NF + f] = qtv;
                ws[OFF_KT + ((size_t)b*NT + tid)*NF + f] = ktv;
            }
        }
        __syncthreads();
        if (tid < NT) {
            float s = cst[7];
            float qi = s * qfv;
            float m0=-1e30f, m1=-1e30f, m2=-1e30f, m3=-1e30f;
            int jj = 0;
            #pragma unroll 2
            for (; jj + 3 < NT; jj += 4) {
                m0 = fmaxf(m0, qi*kv[jj]);
                m1 = fmaxf(m1, qi*kv[jj+1]);
                m2 = fmaxf(m2, qi*kv[jj+2]);
                m3 = fmaxf(m3, qi*kv[jj+3]);
            }
            for (; jj < NT; ++jj) m0 = fmaxf(m0, qi*kv[jj]);
            float m = fmaxf(fmaxf(m0,m1), fmaxf(m2,m3));
            float d0=0.f, d1=0.f, d2=0.f, d3=0.f;
            jj = 0;
            #pragma unroll 2
            for (; jj + 3 < NT; jj += 4) {
                d0 += __expf(qi*kv[jj]   - m);
                d1 += __expf(qi*kv[jj+1] - m);
                d2 += __expf(qi*kv[jj+2] - m);
                d3 += __expf(qi*kv[jj+3] - m);
            }
            for (; jj < NT; ++jj) d0 += __expf(qi*kv[jj] - m);
            float den = (d0+d1)+(d2+d3);
            atomicAdd(&ws[OFF_DF + tid], __expf(qi*kfv - m)/den);
        }
    }
}

__global__ __launch_bounds__(256) void tsm_kernel(float* __restrict__ ws)
{
    __shared__ float dt_acc[NF];
    int tid = threadIdx.x, b = blockIdx.x;
    if (tid < NF) dt_acc[tid] = 0.f;
    __syncthreads();
    if (tid < NT) {
        float s = ws[OFF_CONST+8];
        const float* qp = ws + OFF_QT + ((size_t)b*NT + tid)*NF;
        const float* kp = ws + OFF_KT + ((size_t)b*NT + tid)*NF;
        float q[NF], k[NF];
        #pragma unroll
        for (int i = 0; i < NF; ++i) { q[i] = qp[i]; k[i] = kp[i]; }
        #pragma unroll
        for (int i = 0; i < NF; ++i) {
            float qi = s * q[i];
            float m = -1e30f;
            #pragma unroll
            for (int j = 0; j < NF; ++j) m = fmaxf(m, qi*k[j]);
            float den = 0.f;
            #pragma unroll
            for (int j = 0; j < NF; ++j) den += __expf(qi*k[j] - m);
            atomicAdd(&dt_acc[i], __expf(qi*k[i] - m)/den);
        }
    }
    __syncthreads();
    if (tid < NF) atomicAdd(&ws[OFF_DT + tid], dt_acc[tid]);
}

__global__ __launch_bounds__(256) void t_kernel(const float* __restrict__ x, float* __restrict__ ws)
{
    __shared__ float qs[32*NF], ks[32*NF], dt_acc[NF];
    int tid = threadIdx.x;
    int b  = blockIdx.x >> 3;
    int t0 = (blockIdx.x & 7) * 32;
    int tl = tid & 31, fr = tid >> 5;
    int t = t0 + tl;
    bool act = (fr < NF) && (t < NT);
    if (tid < NF) dt_acc[tid] = 0.f;

    float aq = 0.f, ak = 0.f;
    const float* qeT = ws + OFF_QET;
    const float* keT = ws + OFF_KET;
    if (act) {
        const float* xr = x + (size_t)b*NC*NSP + fr*NT + t;
        #pragma unroll 8
        for (int ch = 0; ch < NC; ++ch) {
            float xv = xr[(size_t)ch*NSP];
            aq = fmaf(qeT[ch], xv, aq);
            ak = fmaf(keT[ch], xv, ak);
        }
    }
    __syncthreads();
    if (act) {
        qs[tl*NF + fr] = aq + ws[OFF_CONST+4];
        ks[tl*NF + fr] = ak + ws[OFF_CONST+5];
    }
    __syncthreads();
    if (act) {
        float s = ws[OFF_CONST+8];
        float qi = s * qs[tl*NF + fr];
        float m = -1e30f;
        #pragma unroll
        for (int j = 0; j < NF; ++j) m = fmaxf(m, qi*ks[tl*NF + j]);
        float den = 0.f;
        #pragma unroll
        for (int j = 0; j < NF; ++j) den += __expf(qi*ks[tl*NF + j] - m);
        atomicAdd(&dt_acc[fr], __expf(qi*ks[tl*NF + fr] - m)/den);
    }
    __syncthreads();
    if (tid < NF) atomicAdd(&ws[OFF_DT + tid], dt_acc[tid]);
}

// --------------------- main2: MFMA straight from global bf16 images,
// register-double-buffered prefetch (fully unrolled -> static slot indices).
__global__ __launch_bounds__(256, 3) void main2_kernel(
    const float* __restrict__ x, const float* __restrict__ ws, float* __restrict__ out)
{
    __shared__ float vsL[128], voL[128], dcL[128], dtfL[128];
    int tid = threadIdx.x;
    int flat = blockIdx.x;                 // 0..895
    int xcd = flat & 7, idx = flat >> 3;   // idx 0..111
    int pair = xcd*56 + (idx >> 1);        // 0..447
    int o0 = (idx & 1) * 128;
    int n0 = (pair % 14) * 128;
    int b  = pair / 14;
    const size_t xbase = (size_t)b * NC * NSP;

    float evs=0.f, evo=0.f, edc=0.f, edtf=0.f;
    if (tid < 128) {
        int o = o0 + tid;
        evs = ws[OFF_VSC+o];
        evo = ws[OFF_VOF+o];
        edc = ws[OFF_DC+o];
        int nn = n0 + tid; if (nn > NSP-1) nn = NSP-1;
        int ff = nn / NT, tt = nn - ff*NT;
        edtf = ws[OFF_DT+ff] + ws[OFF_DF+tt];
    }

    int wv = tid >> 6, ln = tid & 63;
    int quad = ln >> 4, l16 = ln & 15;
    int wr = wv >> 1, wc = wv & 1;

    const u16* wimg = (const u16*)(ws + OFF_WB16) + (size_t)(o0 >> 7) * 32768;
    const unsigned int* ximg = (const unsigned int*)(ws + OFF_XB16)
                             + (size_t)(b*14 + (n0 >> 7)) * 16384;

    float4v acc[4][4] = {};
    short8 afr[2][4];
    int2v blo[2][4], bhi[2][4];

    auto LF = [&](int ks, int s) {
        #pragma unroll
        for (int fr = 0; fr < 4; ++fr)
            afr[s][fr] = *(const short8*)&wimg[ks*4096 + (wr*4+fr)*512 + ln*8];
        #pragma unroll
        for (int fc = 0; fc < 4; ++fc) {
            int nn = wc*64 + fc*16 + l16;
            blo[s][fc] = *(const int2v*)&ximg[ks*2048 + (2*quad)*256 + 2*nn];
            bhi[s][fc] = *(const int2v*)&ximg[ks*2048 + (2*quad+1)*256 + 2*nn];
        }
    };

    LF(0, 0);
    #pragma unroll
    for (int ks = 0; ks < 8; ++ks) {
        const int cur = ks & 1;
        if (ks < 7) LF(ks+1, cur ^ 1);
        #pragma unroll
        for (int fc = 0; fc < 4; ++fc) {
            union { int i4[4]; short8 v; } u;
            u.i4[0] = blo[cur][fc].x; u.i4[1] = blo[cur][fc].y;
            u.i4[2] = bhi[cur][fc].x; u.i4[3] = bhi[cur][fc].y;
            short8 bv = u.v;
            #pragma unroll
            for (int fr = 0; fr < 4; ++fr)
                acc[fr][fc] = __builtin_amdgcn_mfma_f32_16x16x32_bf16(
                    afr[cur][fr], bv, acc[fr][fc], 0, 0, 0);
        }
    }

    if (tid < 128) { vsL[tid]=evs; voL[tid]=evo; dcL[tid]=edc; dtfL[tid]=edtf; }
    __syncthreads();

    #pragma unroll
    for (int fr = 0; fr < 4; ++fr) {
        #pragma unroll
        for (int r = 0; r < 4; ++r) {
            int ol = wr*64 + fr*16 + quad*4 + r;
            int o = o0 + ol;
            float vs = vsL[ol], vo = voL[ol], dcv = dcL[ol];
            const size_t orow = xbase + (size_t)o*NSP;
            #pragma unroll
            for (int fc = 0; fc < 4; ++fc) {
                int nl = wc*64 + fc*16 + l16;
                int nn = n0 + nl;
                if (nn < NSP) {
                    size_t gi = orow + nn;
                    out[gi] = (acc[fr][fc][r]*vs + vo)*(dcv + dtfL[nl]) + x[gi];
                }
            }
        }
    }
}

// --------------------- fallback main GEMM (LDS-staged, double-buffered)
template<int WBF>
__global__ __launch_bounds__(256) void main_kernel(
    const float* __restrict__ x, const float* __restrict__ vw,
    const float* __restrict__ ws, float* __restrict__ out)
{
    __shared__ u16 Ws[2][4096];
    __shared__ unsigned int Xs[2][2048];
    __shared__ float vsL[128], voL[128], dcL[128], dtfL[128];

    int tid = threadIdx.x;
    int flat = blockIdx.x;
    int xcd = flat & 7, idx = flat >> 3;
    int pair = xcd*56 + (idx >> 1);
    int o0 = (idx & 1) * 128;
    int n0 = (pair % 14) * 128;
    int b  = pair / 14;
    const size_t xbase = (size_t)b * NC * NSP;

    if (tid < 128) {
        int o = o0 + tid;
        vsL[tid] = ws[OFF_VSC+o];
        voL[tid] = ws[OFF_VOF+o];
        dcL[tid] = ws[OFF_DC+o];
        int nn = n0 + tid; if (nn > NSP-1) nn = NSP-1;
        int ff = nn / NT, tt = nn - ff*NT;
        dtfL[tid] = ws[OFF_DT+ff] + ws[OFF_DF+tt];
    }

    int wv = tid >> 6, ln = tid & 63;
    int quad = ln >> 4, l16 = ln & 15;
    int wr = wv >> 1, wc = wv & 1;

    float4v acc[4][4] = {};

    int kgs = tid >> 5, nbs = tid & 31;
    int oo = tid >> 1, half = tid & 1;

    const u16* wbg = nullptr;
    if constexpr (WBF) wbg = (const u16*)(ws + OFF_WB16) + (size_t)(o0 >> 7) * 32768;

    int4v wA, wB;
    float wf[16];
    float xv[4][4];

    auto loadW = [&](int ks) {
        if constexpr (WBF) {
            const int4v* wsrc = (const int4v*)(wbg + (size_t)ks*4096);
            wA = wsrc[tid]; wB = wsrc[256 + tid];
        } else {
            const float* wr4 = vw + (size_t)(o0+oo)*NC + ks*32 + half*16;
            #pragma unroll
            for (int c = 0; c < 16; ++c) wf[c] = wr4[c];
        }
    };
    auto loadX = [&](int ks) {
        int nbase = n0 + nbs*4;
        const float* xr = x + xbase + (size_t)(ks*32 + kgs*4)*NSP + nbase;
        if (nbase + 3 < NSP) {
            #pragma unroll
            for (int rr = 0; rr < 4; ++rr)
                #pragma unroll
                for (int i = 0; i < 4; ++i)
                    xv[rr][i] = xr[(size_t)rr*NSP + i];
        } else {
            #pragma unroll
            for (int rr = 0; rr < 4; ++rr)
                #pragma unroll
                for (int i = 0; i < 4; ++i)
                    xv[rr][i] = (nbase + i < NSP) ? xr[(size_t)rr*NSP + i] : 0.f;
        }
    };
    auto storeWX = [&](int bufi) {
        if constexpr (WBF) {
            *(int4v*)&Ws[bufi][tid*8]        = wA;
            *(int4v*)&Ws[bufi][2048 + tid*8] = wB;
        } else {
            union { u16 us[16]; short8 v[2]; } wb;
            #pragma unroll
            for (int c = 0; c < 16; ++c) wb.us[c] = f2b(wf[c]);
            int frg = oo >> 4, o16 = oo & 15;
            #pragma unroll
            for (int qq = 0; qq < 2; ++qq) {
                int qd = 2*half + qq;
                *(short8*)&Ws[bufi][frg*512 + qd*128 + o16*8] = wb.v[qq];
            }
        }
        unsigned int pk[8];
        #pragma unroll
        for (int i = 0; i < 4; ++i)
            #pragma unroll
            for (int jp = 0; jp < 2; ++jp)
                pk[i*2+jp] = pk2(xv[2*jp][i], xv[2*jp+1][i]);
        *(int4v*)&Xs[bufi][XSW(kgs, nbs*8)]     = *(int4v*)&pk[0];
        *(int4v*)&Xs[bufi][XSW(kgs, nbs*8 + 4)] = *(int4v*)&pk[4];
    };

    loadW(0); loadX(0);
    storeWX(0);
    __syncthreads();

    for (int ks = 0; ks < 8; ++ks) {
        int cur = ks & 1;
        if (ks < 7) { loadW(ks+1); loadX(ks+1); }

        short8 afr[4], bfr[4];
        #pragma unroll
        for (int fr = 0; fr < 4; ++fr)
            afr[fr] = *(short8*)&Ws[cur][(wr*4+fr)*512 + ln*8];
        #pragma unroll
        for (int fc = 0; fc < 4; ++fc) {
            int nn = wc*64 + fc*16 + l16;
            int2v lo = *(int2v*)&Xs[cur][XSW(2*quad,   2*nn)];
            int2v hi = *(int2v*)&Xs[cur][XSW(2*quad+1, 2*nn)];
            union { int i4[4]; short8 v; } u;
            u.i4[0] = lo.x; u.i4[1] = lo.y; u.i4[2] = hi.x; u.i4[3] = hi.y;
            bfr[fc] = u.v;
        }
        #pragma unroll
        for (int fr = 0; fr < 4; ++fr)
            #pragma unroll
            for (int fc = 0; fc < 4; ++fc)
                acc[fr][fc] = __builtin_amdgcn_mfma_f32_16x16x32_bf16(
                    afr[fr], bfr[fc], acc[fr][fc], 0, 0, 0);

        if (ks < 7) storeWX(cur ^ 1);
        __syncthreads();
    }

    #pragma unroll
    for (int fr = 0; fr < 4; ++fr) {
        #pragma unroll
        for (int r = 0; r < 4; ++r) {
            int ol = wr*64 + fr*16 + quad*4 + r;
            int o = o0 + ol;
            float vs = vsL[ol], vo = voL[ol], dcv = dcL[ol];
            const size_t orow = xbase + (size_t)o*NSP;
            #pragma unroll
            for (int fc = 0; fc < 4; ++fc) {
                int nl = wc*64 + fc*16 + l16;
                int nn = n0 + nl;
                if (nn < NSP) {
                    size_t gi = orow + nn;
                    out[gi] = (acc[fr][fc][r]*vs + vo)*(dcv + dtfL[nl]) + x[gi];
                }
            }
        }
    }
}

extern "C" void kernel_launch(void* const* d_in, const int* in_sizes, int n_in,
                              void* d_out, int out_size, void* d_ws, size_t ws_size,
                              hipStream_t stream)
{
    const float* x    = (const float*)d_in[0];
    const float* qc_w = (const float*)d_in[1];  const float* qc_bn = (const float*)d_in[2];
    const float* kc_w = (const float*)d_in[3];  const float* kc_bn = (const float*)d_in[4];
    const float* lc_bn= (const float*)d_in[5];
    const float* qf_w = (const float*)d_in[6];  const float* qf_bn = (const float*)d_in[7];
    const float* kf_w = (const float*)d_in[8];  const float* kf_bn = (const float*)d_in[9];
    const float* lf_bn= (const float*)d_in[10];
    const float* qt_w = (const float*)d_in[11]; const float* qt_bn = (const float*)d_in[12];
    const float* kt_w = (const float*)d_in[13]; const float* kt_bn = (const float*)d_in[14];
    const float* lt_bn= (const float*)d_in[15];
    const float* v_w  = (const float*)d_in[16]; const float* v_b   = (const float*)d_in[17];
    const float* v_bn = (const float*)d_in[18];
    float* ws = (float*)d_ws;
    float* out = (float*)d_out;

    int fuse_t = (ws_size >= (size_t)WS2_END * sizeof(float)) ? 1 : 0;
    int wbf    = (ws_size >= (size_t)WS3_END * sizeof(float)) ? 1 : 0;
    int newq   = (ws_size >= (size_t)WS4_END * sizeof(float)) ? 1 : 0;
    int xb     = (ws_size >= (size_t)WS5_END * sizeof(float)) ? 1 : 0;

    prep_kernel<<<wbf ? 37 : 25, 256, 0, stream>>>(qc_w,qc_bn,kc_w,kc_bn,lc_bn,
                                                   qf_w,qf_bn,kf_w,kf_bn,lf_bn,
                                                   qt_w,qt_bn,kt_w,kt_bn,lt_bn,
                                                   v_b,v_bn,v_w,ws,newq);
    if (newq) {
        qv_kernel<<<4480, 512, 0, stream>>>(x, ws, xb);
        sm_kernel<<<256, 256, 0, stream>>>(ws);
    } else {
        qkt_kernel<<<NB*NF*2, 512, 0, stream>>>(x, ws, fuse_t);
        if (fuse_t) tsm_kernel<<<NB, 256, 0, stream>>>(ws);
        else        t_kernel<<<NB*8, 256, 0, stream>>>(x, ws);
    }
    if (xb && wbf)
        main2_kernel<<<896, 256, 0, stream>>>(x, ws, out);
    else if (wbf)
        main_kernel<1><<<896, 256, 0, stream>>>(x, v_w, ws, out);
    else
        main_kernel<0><<<896, 256, 0, stream>>>(x, v_w, ws, out);
}

// Round 7
// 214.074 us; speedup vs baseline: 1.0546x; 1.0053x over previous
//
#include <hip/hip_runtime.h>

typedef unsigned short u16;
typedef __attribute__((ext_vector_type(8))) short short8;
typedef __attribute__((ext_vector_type(4))) float float4v;
typedef __attribute__((ext_vector_type(4))) int int4v;
typedef __attribute__((ext_vector_type(2))) int int2v;

#define EPS 1e-5f
#define NC 256
#define NT 251
#define NF 7
#define NSP 1757   // NF*NT
#define NB 32

// workspace layout (float offsets)
#define OFF_QEC 0
#define OFF_KEC 256
#define OFF_QEF 512
#define OFF_KEF 768
#define OFF_QET 1024
#define OFF_KET 1280
#define OFF_VSC 1536
#define OFF_VOF 1792
#define OFF_CONST 2048   // [0..5]=q/k consts c,f,t  [6]=s_c [7]=s_f [8]=s_t
#define OFF_DC 2064      // 256
#define OFF_DF 2320      // 256 (251 used)
#define OFF_DT 2576      // 16 (7 used)
#define WS_END 2592
// fused-t staging (old layout [b][t][f] for fallback; new path uses [b][sp])
#define OFF_QT 2592            // 56320
#define OFF_KT (OFF_QT+56320)  // 56320
#define WS2_END (OFF_KT+56320) // 115232 floats
// pre-tiled bf16 v_w in MFMA LDS layout
#define OFF_WB16 WS2_END
#define WS3_END (WS2_END+32768) // 148000 floats
// new-path staging: qf/kf [b][sp], qc/kc [n][ch]
#define OFF_QF2 WS3_END              // 56320
#define OFF_KF2 (OFF_QF2+56320)      // 56320
#define OFF_QCS (OFF_KF2+56320)      // 57344
#define OFF_KCS (OFF_QCS+57344)      // 57344
#define WS4_END (OFF_KCS+57344)      // 375328 floats ≈ 1.43 MB
// bf16 x image in main's B-fragment order: [b][nchunk14][ks8][kg8][w256] u32
#define OFF_XB16 WS4_END
#define XB16_U32 (448*16384)         // 7340032 u32
#define WS5_END (OFF_XB16 + XB16_U32) // 7715360 floats ≈ 29.4 MB

// Xs swizzle for fallback main_kernel LDS (4-way -> 2-way on b64 frag reads)
#define XSW(kg, w) ((kg)*256 + ((w) ^ ((((kg)>>1)&3)<<3)))

__device__ __forceinline__ u16 f2b(float f) {   // fp32 -> bf16 RNE
    unsigned int u = __float_as_uint(f);
    return (u16)((u + 0x7FFFu + ((u >> 16) & 1u)) >> 16);
}
__device__ __forceinline__ unsigned int pk2(float a, float b) {
    return (unsigned int)f2b(a) | ((unsigned int)f2b(b) << 16);
}

// ---------------------------------------------------------------- prep
// blocks 0..23: matvecs; 24: scalars+zero small; 25..32: WB16 tiling (wbf);
// 33..36: zero QF2/KF2/QT/KT for the atomic qv path (nz)
__global__ __launch_bounds__(256) void prep_kernel(
    const float* qc_w, const float* qc_bn, const float* kc_w, const float* kc_bn, const float* lc_bn,
    const float* qf_w, const float* qf_bn, const float* kf_w, const float* kf_bn, const float* lf_bn,
    const float* qt_w, const float* qt_bn, const float* kt_w, const float* kt_bn, const float* lt_bn,
    const float* v_b, const float* v_bn, const float* v_w, float* ws, int nz)
{
    int tid = threadIdx.x;
    int blk = blockIdx.x;
    __shared__ float sc[256];
    __shared__ float red[256];
    if (blk < 24) {
        int m = blk >> 2, j = blk & 3;
        const float* w; const float* bn; float* out; int O;
        switch (m) {
            case 0: w=qc_w; bn=qc_bn; out=ws+OFF_QEC; O=NT; break;
            case 1: w=kc_w; bn=kc_bn; out=ws+OFF_KEC; O=NT; break;
            case 2: w=qf_w; bn=qf_bn; out=ws+OFF_QEF; O=NC; break;
            case 3: w=kf_w; bn=kf_bn; out=ws+OFF_KEF; O=NC; break;
            case 4: w=qt_w; bn=qt_bn; out=ws+OFF_QET; O=NC; break;
            default: w=kt_w; bn=kt_bn; out=ws+OFF_KET; O=NC; break;
        }
        if (tid < O) sc[tid] = bn[tid] * rsqrtf(bn[3*O+tid] + EPS);
        __syncthreads();
        int tl = tid & 63, kc4 = tid >> 6;
        int t = j*64 + tl;
        float acc = 0.f;
        if (t < O) {
            #pragma unroll 8
            for (int o = kc4; o < O; o += 4)
                acc = fmaf(sc[o], w[(size_t)o*O + t], acc);
        }
        red[tid] = acc;
        __syncthreads();
        if (tid < 64) {
            int tt = j*64 + tid;
            if (tt < O)
                out[tt] = (red[tid] + red[tid+64] + red[tid+128] + red[tid+192]) / (float)O;
        }
        if (j == 0) {
            float bs = 0.f;
            if (tid < O) bs = bn[O+tid] - bn[2*O+tid]*sc[tid];
            __syncthreads();
            red[tid] = bs; __syncthreads();
            for (int s2 = 128; s2 > 0; s2 >>= 1) { if (tid < s2) red[tid] += red[tid+s2]; __syncthreads(); }
            if (tid == 0) ws[OFF_CONST+m] = red[0] / (float)O;
        }
    } else if (blk == 24) {
        if (tid < NC) {
            float s = v_bn[tid] * rsqrtf(v_bn[3*NC+tid] + EPS);
            ws[OFF_VSC+tid] = s;
            ws[OFF_VOF+tid] = v_bn[NC+tid] - v_bn[2*NC+tid]*s + v_b[tid]*s;
        }
        if (tid == 0) {
            ws[OFF_CONST+6] = lc_bn[0] * rsqrtf(lc_bn[3] + EPS);
            ws[OFF_CONST+7] = lf_bn[0] * rsqrtf(lf_bn[3] + EPS);
            ws[OFF_CONST+8] = lt_bn[0] * rsqrtf(lt_bn[3] + EPS);
        }
        for (int i = tid; i < WS_END - OFF_DC; i += 256) ws[OFF_DC + i] = 0.f;
    } else if (blk < 33) {
        // blocks 25..32: tile v_w -> bf16 MFMA layout. Coalesced float4 reads,
        // scattered 8B writes.
        u16* wb = (u16*)(ws + OFF_WB16);
        int base = (blk - 25) * 8192;   // elements of v_w
        for (int i4 = tid; i4 < 2048; i4 += 256) {
            int e = base + i4*4;
            int o = e >> 8, k = e & 255;
            float4v v = *(const float4v*)(v_w + e);
            u16 h0 = f2b(v.x), h1 = f2b(v.y), h2 = f2b(v.z), h3 = f2b(v.w);
            int r = ((o>>7)<<3) | (k>>5);
            int q = (((o>>4)&7)<<9) | (((k>>3)&3)<<7) | ((o&15)<<3) | (k&7);
            unsigned long long pk = (unsigned long long)h0 | ((unsigned long long)h1<<16)
                                  | ((unsigned long long)h2<<32) | ((unsigned long long)h3<<48);
            *(unsigned long long*)&wb[(r<<12) | q] = pk;
        }
    } else {
        // blocks 33..36: zero the atomic accumulators (only in newq mode)
        if (!nz) return;
        int z = blk - 33;
        float* p;
        switch (z) {
            case 0: p = ws + OFF_QF2; break;
            case 1: p = ws + OFF_KF2; break;
            case 2: p = ws + OFF_QT;  break;
            default: p = ws + OFF_KT; break;
        }
        float4v zv = {0.f, 0.f, 0.f, 0.f};
        for (int i = tid; i < 14080; i += 256) ((float4v*)p)[i] = zv;
    }
}

// --------------- qv/kv computation, single pass structure, staged to ws
// blocks 0..895   : ft-part, (pair, ch-half). 128 ch x 128 sp per block.
//                   atomicAdd partials -> QF2/KF2/QT/KT (consts added in sm).
//                   also emits the bf16 x-image (its ch-half) if pack.
// blocks 896..4479: c-part, (n, 16ch-tile) -> QCS/KCS (raw, consts in sm).
__global__ __launch_bounds__(512) void qv_kernel(const float* __restrict__ x,
                                                 float* __restrict__ ws, int pack)
{
    __shared__ float lds[6144];
    int tid = threadIdx.x;
    int blk = blockIdx.x;

    if (blk < 896) {
        // ---------- ft-part ----------
        int half = blk & 1;
        int pairid = blk >> 1;           // 0..447
        int b = pairid / 14, nchunk = pairid % 14;
        int n0 = nchunk * 128;
        int spg = tid & 31, chg = tid >> 5;   // 16 chg-groups x 8 ch each (this half)
        // stage this half's e-vectors: [qf 4096][kf 4224][qt 4352][kt 4480], 128 each
        if (tid < 128) {
            lds[4096+tid] = ws[OFF_QEF + half*128 + tid];
            lds[4352+tid] = ws[OFF_QET + half*128 + tid];
        } else if (tid < 256) {
            int u = tid - 128;
            lds[4224+u] = ws[OFF_KEF + half*128 + u];
            lds[4480+u] = ws[OFF_KET + half*128 + u];
        }
        __syncthreads();
        const size_t xbase = (size_t)b*NC*NSP;
        int sp0 = n0 + spg*4;
        bool full = (sp0 + 3 < NSP);
        unsigned int* ximg = nullptr;
        if (pack) ximg = (unsigned int*)(ws + OFF_XB16) + (size_t)(b*14 + nchunk)*16384;

        float qf[4]={0,0,0,0}, kf[4]={0,0,0,0}, qt[4]={0,0,0,0}, kt[4]={0,0,0,0};
        #pragma unroll
        for (int ii = 0; ii < 2; ++ii) {
            int chl0 = chg*8 + ii*4;          // local ch base 0..124
            int ch0 = half*128 + chl0;        // global ch base
            float xv4[4][4];
            #pragma unroll
            for (int cc = 0; cc < 4; ++cc) {
                int ch = ch0 + cc;
                const float* xr = x + xbase + (size_t)ch*NSP + sp0;
                if (full) {
                    xv4[cc][0]=xr[0]; xv4[cc][1]=xr[1]; xv4[cc][2]=xr[2]; xv4[cc][3]=xr[3];
                } else {
                    #pragma unroll
                    for (int j = 0; j < 4; ++j) xv4[cc][j] = (sp0+j < NSP) ? xr[j] : 0.f;
                }
                float eqf = lds[4096+chl0+cc], ekf = lds[4224+chl0+cc];
                float eqt = lds[4352+chl0+cc], ekt = lds[4480+chl0+cc];
                #pragma unroll
                for (int j = 0; j < 4; ++j) {
                    qf[j] = fmaf(eqf, xv4[cc][j], qf[j]);
                    kf[j] = fmaf(ekf, xv4[cc][j], kf[j]);
                    qt[j] = fmaf(eqt, xv4[cc][j], qt[j]);
                    kt[j] = fmaf(ekt, xv4[cc][j], kt[j]);
                }
            }
            if (pack) {
                int kgsg = ch0 >> 2;          // half*32 + chg*2 + ii  (0..63)
                int ks = kgsg >> 3, kgl = kgsg & 7;
                unsigned int* dst = ximg + ks*2048 + kgl*256 + spg*8;
                unsigned int pk[8];
                #pragma unroll
                for (int i = 0; i < 4; ++i) {
                    pk[i*2+0] = pk2(xv4[0][i], xv4[1][i]);
                    pk[i*2+1] = pk2(xv4[2][i], xv4[3][i]);
                }
                *(int4v*)&dst[0] = *(int4v*)&pk[0];
                *(int4v*)&dst[4] = *(int4v*)&pk[4];
            }
        }
        // fold chg-pairs across wave halves (lanes 0-31 <-> 32-63)
        #pragma unroll
        for (int j = 0; j < 4; ++j) {
            qf[j] += __shfl_xor(qf[j], 32);
            kf[j] += __shfl_xor(kf[j], 32);
            qt[j] += __shfl_xor(qt[j], 32);
            kt[j] += __shfl_xor(kt[j], 32);
        }
        int wv = tid >> 6, ln = tid & 63;
        if (ln < 32) {
            // [v(16)][wv(8)][spg(32)]: bank = spg -> conflict-free
            #pragma unroll
            for (int j = 0; j < 4; ++j) {
                lds[(j)*256     + wv*32 + ln] = qf[j];
                lds[(4+j)*256   + wv*32 + ln] = kf[j];
                lds[(8+j)*256   + wv*32 + ln] = qt[j];
                lds[(12+j)*256  + wv*32 + ln] = kt[j];
            }
        }
        __syncthreads();
        if (tid < 32) {
            float acc[16];
            #pragma unroll
            for (int v = 0; v < 16; ++v) {
                float s = 0.f;
                #pragma unroll
                for (int w = 0; w < 8; ++w) s += lds[v*256 + w*32 + tid];
                acc[v] = s;
            }
            int sp0w = n0 + tid*4;
            #pragma unroll
            for (int j = 0; j < 4; ++j) {
                if (sp0w + j < NSP) {
                    size_t o = (size_t)b*1760 + sp0w + j;
                    atomicAdd(&ws[OFF_QF2 + o], acc[j]);
                    atomicAdd(&ws[OFF_KF2 + o], acc[4+j]);
                    atomicAdd(&ws[OFF_QT  + o], acc[8+j]);
                    atomicAdd(&ws[OFF_KT  + o], acc[12+j]);
                }
            }
        }
    } else {
        // ---------- c-part: 16-row tiles ----------
        int blk2 = blk - 896;            // 0..3583
        int n = blk2 >> 4, cb = blk2 & 15;
        int b = n / NF, f = n % NF;
        const float* xb = x + (size_t)b*NC*NSP + (size_t)f*NT + (size_t)(cb*16)*NSP;
        // qe at 4112, ke at 4368; tile [16][257] at 0; pq 4624, pk 5136
        if (tid < NT) lds[4112+tid] = ws[OFF_QEC+tid];
        else if (tid >= 256 && tid < 256+NT) lds[4368+tid-256] = ws[OFF_KEC+tid-256];
        int lr = tid >> 8, lane = tid & 255;
        #pragma unroll
        for (int i = 0; i < 8; ++i) {     // full unroll: 8 loads in flight
            int r = 2*i + lr;
            if (lane < NT) lds[r*257 + lane] = xb[(size_t)r*NSP + lane];
        }
        __syncthreads();
        int r = tid & 15, seg = tid >> 4;  // 16 r x 32 seg (8 t each)
        int t0 = seg*8, t1 = (seg == 31) ? NT : t0+8;
        float qa = 0.f, ka = 0.f;
        #pragma unroll 8
        for (int t = t0; t < t1; ++t) {
            float xv = lds[r*257 + t];
            qa = fmaf(lds[4112+t], xv, qa);
            ka = fmaf(lds[4368+t], xv, ka);
        }
        lds[4624 + seg*16 + r] = qa;      // addr = tid: conflict-free
        lds[5136 + seg*16 + r] = ka;
        __syncthreads();
        if (tid < 32) {
            int rr = tid & 15, which = tid >> 4;
            int base = (which ? 5136 : 4624) + rr;
            float s = 0.f;
            #pragma unroll
            for (int sg = 0; sg < 32; ++sg) s += lds[base + sg*16];
            int ch = cb*16 + rr;
            if (which == 0) ws[OFF_QCS + n*256 + ch] = s;
            else            ws[OFF_KCS + n*256 + ch] = s;
        }
    }
}

// --------------- all three diag softmaxes from staged q/k (adds consts)
__global__ __launch_bounds__(256) void sm_kernel(float* __restrict__ ws)
{
    __shared__ float kv[NC];
    __shared__ float kv2[NT];
    __shared__ float dt_acc[NF];
    int tid = threadIdx.x, blk = blockIdx.x;
    const float* cst = ws + OFF_CONST;

    if (blk < 224) {
        int b = blk / NF, f = blk % NF;
        float qcv = ws[OFF_QCS + blk*256 + tid] + cst[0];
        float kcv = ws[OFF_KCS + blk*256 + tid] + cst[1];
        kv[tid] = kcv;
        float qfv = 0.f, kfv = 0.f;
        if (tid < NT) {
            size_t o = (size_t)b*1760 + f*NT + tid;
            qfv = ws[OFF_QF2 + o] + cst[2];
            kfv = ws[OFF_KF2 + o] + cst[3];
            kv2[tid] = kfv;
        }
        __syncthreads();
        {   // c diag softmax
            float s = cst[6];
            float qi = s * qcv;
            float m0=-1e30f, m1=-1e30f, m2=-1e30f, m3=-1e30f;
            #pragma unroll 2
            for (int jj = 0; jj < NC; jj += 4) {
                m0 = fmaxf(m0, qi*kv[jj]);
                m1 = fmaxf(m1, qi*kv[jj+1]);
                m2 = fmaxf(m2, qi*kv[jj+2]);
                m3 = fmaxf(m3, qi*kv[jj+3]);
            }
            float m = fmaxf(fmaxf(m0,m1), fmaxf(m2,m3));
            float d0=0.f, d1=0.f, d2=0.f, d3=0.f;
            #pragma unroll 2
            for (int jj = 0; jj < NC; jj += 4) {
                d0 += __expf(qi*kv[jj]   - m);
                d1 += __expf(qi*kv[jj+1] - m);
                d2 += __expf(qi*kv[jj+2] - m);
                d3 += __expf(qi*kv[jj+3] - m);
            }
            float den = (d0+d1)+(d2+d3);
            atomicAdd(&ws[OFF_DC + tid], __expf(qi*kcv - m)/den);
        }
        if (tid < NT) {   // f diag softmax
            float s = cst[7];
            float qi = s * qfv;
            float m0=-1e30f, m1=-1e30f, m2=-1e30f, m3=-1e30f;
            int jj = 0;
            #pragma unroll 2
            for (; jj + 3 < NT; jj += 4) {
                m0 = fmaxf(m0, qi*kv2[jj]);
                m1 = fmaxf(m1, qi*kv2[jj+1]);
                m2 = fmaxf(m2, qi*kv2[jj+2]);
                m3 = fmaxf(m3, qi*kv2[jj+3]);
            }
            for (; jj < NT; ++jj) m0 = fmaxf(m0, qi*kv2[jj]);
            float m = fmaxf(fmaxf(m0,m1), fmaxf(m2,m3));
            float d0=0.f, d1=0.f, d2=0.f, d3=0.f;
            jj = 0;
            #pragma unroll 2
            for (; jj + 3 < NT; jj += 4) {
                d0 += __expf(qi*kv2[jj]   - m);
                d1 += __expf(qi*kv2[jj+1] - m);
                d2 += __expf(qi*kv2[jj+2] - m);
                d3 += __expf(qi*kv2[jj+3] - m);
            }
            for (; jj < NT; ++jj) d0 += __expf(qi*kv2[jj] - m);
            float den = (d0+d1)+(d2+d3);
            atomicAdd(&ws[OFF_DF + tid], __expf(qi*kfv - m)/den);
        }
    } else {
        int b = blk - 224;
        if (tid < NF) dt_acc[tid] = 0.f;
        __syncthreads();
        if (tid < NT) {
            float s = cst[8];
            float q[NF], k[NF];
            #pragma unroll
            for (int i = 0; i < NF; ++i) {
                size_t o = (size_t)b*1760 + i*NT + tid;
                q[i] = ws[OFF_QT + o] + cst[4];
                k[i] = ws[OFF_KT + o] + cst[5];
            }
            #pragma unroll
            for (int i = 0; i < NF; ++i) {
                float qi = s * q[i];
                float m = -1e30f;
                #pragma unroll
                for (int j = 0; j < NF; ++j) m = fmaxf(m, qi*k[j]);
                float den = 0.f;
                #pragma unroll
                for (int j = 0; j < NF; ++j) den += __expf(qi*k[j] - m);
                atomicAdd(&dt_acc[i], __expf(qi*k[i] - m)/den);
            }
        }
        __syncthreads();
        if (tid < NF) atomicAdd(&ws[OFF_DT + tid], dt_acc[tid]);
    }
}

// ------------ OLD-PATH kernels (fallback when ws too small) ------------
__global__ __launch_bounds__(512) void qkt_kernel(const float* __restrict__ x,
                                                  float* __restrict__ ws, int fuse_t)
{
    __shared__ float kv[NC];
    __shared__ float p0[512], p1[512], p2[512], p3[512];
    int tid = threadIdx.x;
    int bid = blockIdx.x;
    int n = bid >> 1, role = bid & 1;
    int b = n / NF, f = n % NF;
    const float* xb = x + (size_t)b*NC*NSP + (size_t)f*NT;
    const float* cst = ws + OFF_CONST;
    int half = tid >> 8, lid = tid & 255;

    if (role == 0) {
        const float* xrow = xb + (size_t)lid*NSP;
        const float* qeC = ws + OFF_QEC;  const float* keC = ws + OFF_KEC;
        float qc = 0.f, kc = 0.f;
        int t0 = half ? 126 : 0, t1 = half ? NT : 126;
        #pragma unroll 16
        for (int t = t0; t < t1; ++t) {
            float xv = xrow[t];
            qc = fmaf(qeC[t], xv, qc);
            kc = fmaf(keC[t], xv, kc);
        }
        p0[tid] = qc; p1[tid] = kc;
        __syncthreads();
        if (tid < 256) {
            qc = p0[tid] + p0[tid+256] + cst[0];
            kc = p1[tid] + p1[tid+256] + cst[1];
            kv[tid] = kc;
        }
        __syncthreads();
        if (tid < 256) {
            float s = cst[6];
            float qi = s * qc;
            float m0=-1e30f, m1=-1e30f, m2=-1e30f, m3=-1e30f;
            #pragma unroll 2
            for (int jj = 0; jj < NC; jj += 4) {
                m0 = fmaxf(m0, qi*kv[jj]);
                m1 = fmaxf(m1, qi*kv[jj+1]);
                m2 = fmaxf(m2, qi*kv[jj+2]);
                m3 = fmaxf(m3, qi*kv[jj+3]);
            }
            float m = fmaxf(fmaxf(m0,m1), fmaxf(m2,m3));
            float d0=0.f, d1=0.f, d2=0.f, d3=0.f;
            #pragma unroll 2
            for (int jj = 0; jj < NC; jj += 4) {
                d0 += __expf(qi*kv[jj]   - m);
                d1 += __expf(qi*kv[jj+1] - m);
                d2 += __expf(qi*kv[jj+2] - m);
                d3 += __expf(qi*kv[jj+3] - m);
            }
            float den = (d0+d1)+(d2+d3);
            atomicAdd(&ws[OFF_DC + tid], __expf(qi*kv[tid] - m)/den);
        }
    } else {
        float qf=0.f, kf=0.f, qt=0.f, kt=0.f;
        if (lid < NT) {
            const float* xc = xb + lid + (size_t)(half*128)*NSP;
            const float* qeF = ws + OFF_QEF + half*128;  const float* keF = ws + OFF_KEF + half*128;
            const float* qeT = ws + OFF_QET + half*128;  const float* keT = ws + OFF_KET + half*128;
            #pragma unroll 8
            for (int ch = 0; ch < 128; ++ch) {
                float xv = xc[(size_t)ch*NSP];
                qf = fmaf(qeF[ch], xv, qf);
                kf = fmaf(keF[ch], xv, kf);
                qt = fmaf(qeT[ch], xv, qt);
                kt = fmaf(keT[ch], xv, kt);
            }
        }
        p0[tid]=qf; p1[tid]=kf; p2[tid]=qt; p3[tid]=kt;
        __syncthreads();
        float qfv=0.f, kfv=0.f;
        if (tid < NT) {
            qfv = p0[tid] + p0[tid+256] + cst[2];
            kfv = p1[tid] + p1[tid+256] + cst[3];
            float qtv = p2[tid] + p2[tid+256] + cst[4];
            float ktv = p3[tid] + p3[tid+256] + cst[5];
            kv[tid] = kfv;
            if (fuse_t) {
                ws[OFF_QT + ((size_t)b*NT + tid)*NF + f] = qtv;
                ws[OFF_KT + ((size_t)b*NT + tid)*NF + f] = ktv;
            }
        }
        __syncthreads();
        if (tid < NT) {
            float s = cst[7];
            float qi = s * qfv;
            float m0=-1e30f, m1=-1e30f, m2=-1e30f, m3=-1e30f;
            int jj = 0;
            #pragma unroll 2
            for (; jj + 3 < NT; jj += 4) {
                m0 = fmaxf(m0, qi*kv[jj]);
                m1 = fmaxf(m1, qi*kv[jj+1]);
                m2 = fmaxf(m2, qi*kv[jj+2]);
                m3 = fmaxf(m3, qi*kv[jj+3]);
            }
            for (; jj < NT; ++jj) m0 = fmaxf(m0, qi*kv[jj]);
            float m = fmaxf(fmaxf(m0,m1), fmaxf(m2,m3));
            float d0=0.f, d1=0.f, d2=0.f, d3=0.f;
            jj = 0;
            #pragma unroll 2
            for (; jj + 3 < NT; jj += 4) {
                d0 += __expf(qi*kv[jj]   - m);
                d1 += __expf(qi*kv[jj+1] - m);
                d2 += __expf(qi*kv[jj+2] - m);
                d3 += __expf(qi*kv[jj+3] - m);
            }
            for (; jj < NT; ++jj) d0 += __expf(qi*kv[jj] - m);
            float den = (d0+d1)+(d2+d3);
            atomicAdd(&ws[OFF_DF + tid], __expf(qi*kfv - m)/den);
        }
    }
}

__global__ __launch_bounds__(256) void tsm_kernel(float* __restrict__ ws)
{
    __shared__ float dt_acc[NF];
    int tid = threadIdx.x, b = blockIdx.x;
    if (tid < NF) dt_acc[tid] = 0.f;
    __syncthreads();
    if (tid < NT) {
        float s = ws[OFF_CONST+8];
        const float* qp = ws + OFF_QT + ((size_t)b*NT + tid)*NF;
        const float* kp = ws + OFF_KT + ((size_t)b*NT + tid)*NF;
        float q[NF], k[NF];
        #pragma unroll
        for (int i = 0; i < NF; ++i) { q[i] = qp[i]; k[i] = kp[i]; }
        #pragma unroll
        for (int i = 0; i < NF; ++i) {
            float qi = s * q[i];
            float m = -1e30f;
            #pragma unroll
            for (int j = 0; j < NF; ++j) m = fmaxf(m, qi*k[j]);
            float den = 0.f;
            #pragma unroll
            for (int j = 0; j < NF; ++j) den += __expf(qi*k[j] - m);
            atomicAdd(&dt_acc[i], __expf(qi*k[i] - m)/den);
        }
    }
    __syncthreads();
    if (tid < NF) atomicAdd(&ws[OFF_DT + tid], dt_acc[tid]);
}

__global__ __launch_bounds__(256) void t_kernel(const float* __restrict__ x, float* __restrict__ ws)
{
    __shared__ float qs[32*NF], ks[32*NF], dt_acc[NF];
    int tid = threadIdx.x;
    int b  = blockIdx.x >> 3;
    int t0 = (blockIdx.x & 7) * 32;
    int tl = tid & 31, fr = tid >> 5;
    int t = t0 + tl;
    bool act = (fr < NF) && (t < NT);
    if (tid < NF) dt_acc[tid] = 0.f;

    float aq = 0.f, ak = 0.f;
    const float* qeT = ws + OFF_QET;
    const float* keT = ws + OFF_KET;
    if (act) {
        const float* xr = x + (size_t)b*NC*NSP + fr*NT + t;
        #pragma unroll 8
        for (int ch = 0; ch < NC; ++ch) {
            float xv = xr[(size_t)ch*NSP];
            aq = fmaf(qeT[ch], xv, aq);
            ak = fmaf(keT[ch], xv, ak);
        }
    }
    __syncthreads();
    if (act) {
        qs[tl*NF + fr] = aq + ws[OFF_CONST+4];
        ks[tl*NF + fr] = ak + ws[OFF_CONST+5];
    }
    __syncthreads();
    if (act) {
        float s = ws[OFF_CONST+8];
        float qi = s * qs[tl*NF + fr];
        float m = -1e30f;
        #pragma unroll
        for (int j = 0; j < NF; ++j) m = fmaxf(m, qi*ks[tl*NF + j]);
        float den = 0.f;
        #pragma unroll
        for (int j = 0; j < NF; ++j) den += __expf(qi*ks[tl*NF + j] - m);
        atomicAdd(&dt_acc[fr], __expf(qi*ks[tl*NF + fr] - m)/den);
    }
    __syncthreads();
    if (tid < NF) atomicAdd(&ws[OFF_DT + tid], dt_acc[tid]);
}

// --------------------- main2 v3: 64x64 tiles, 3584 blocks, 64-VGPR tier.
// MFMA straight from global bf16 images; register double-buffer prefetch.
__global__ __launch_bounds__(256, 8) void main2_kernel(
    const float* __restrict__ x, const float* __restrict__ ws, float* __restrict__ out)
{
    __shared__ float vsL[64], voL[64], dcL[64], dtfL[64];
    int tid = threadIdx.x;
    // XCD decode: 8 sub-tiles (4 o-tiles x 2 n-halves) of one (b,nchunk) group
    // stay on one XCD -> its 64KB ximg slice is L2-hot.
    int flat = blockIdx.x;                 // 0..3583
    int xcd = flat & 7, i = flat >> 3;     // i 0..447
    int grp = xcd*56 + (i >> 3);           // 0..447 = b*14 + nchunk
    int sub = i & 7;
    int ot = sub >> 1, nh = sub & 1;
    int b = grp / 14, nch = grp % 14;
    int n0 = nch*128 + nh*64;
    int o0 = ot*64;
    const size_t xbase = (size_t)b * NC * NSP;

    float evs=0.f, evo=0.f, edc=0.f, edtf=0.f;
    if (tid < 64) {
        int o = o0 + tid;
        evs = ws[OFF_VSC+o];
        evo = ws[OFF_VOF+o];
        edc = ws[OFF_DC+o];
        int nn = n0 + tid; if (nn > NSP-1) nn = NSP-1;
        int ff = nn / NT, tt = nn - ff*NT;
        edtf = ws[OFF_DT+ff] + ws[OFF_DF+tt];
    }

    int wv = tid >> 6, ln = tid & 63;
    int quad = ln >> 4, l16 = ln & 15;
    int wr = wv >> 1, wc = wv & 1;     // wr: o-half (32), wc: n-half (32)

    // A: frag f of the 64-o tile is global frag (ot&1)*4 + f within o_blk (ot>>1)
    const u16* wimg = (const u16*)(ws + OFF_WB16)
                    + (size_t)(ot >> 1) * 32768 + (size_t)((ot & 1) * 4) * 512;
    const unsigned int* ximg = (const unsigned int*)(ws + OFF_XB16)
                             + (size_t)grp * 16384;

    float4v acc[2][2] = {};
    short8 afr[2][2];
    int2v blo[2][2], bhi[2][2];

    auto LF = [&](int ks, int s) {
        #pragma unroll
        for (int fr = 0; fr < 2; ++fr)
            afr[s][fr] = *(const short8*)&wimg[ks*4096 + (wr*2+fr)*512 + ln*8];
        #pragma unroll
        for (int fc = 0; fc < 2; ++fc) {
            int nn128 = nh*64 + wc*32 + fc*16 + l16;
            blo[s][fc] = *(const int2v*)&ximg[ks*2048 + (2*quad)*256 + 2*nn128];
            bhi[s][fc] = *(const int2v*)&ximg[ks*2048 + (2*quad+1)*256 + 2*nn128];
        }
    };

    LF(0, 0);
    #pragma unroll
    for (int ks = 0; ks < 8; ++ks) {
        const int cur = ks & 1;
        if (ks < 7) LF(ks+1, cur ^ 1);     // next-step loads in flight over MFMAs
        #pragma unroll
        for (int fc = 0; fc < 2; ++fc) {
            union { int i4[4]; short8 v; } u;
            u.i4[0] = blo[cur][fc].x; u.i4[1] = blo[cur][fc].y;
            u.i4[2] = bhi[cur][fc].x; u.i4[3] = bhi[cur][fc].y;
            short8 bv = u.v;
            #pragma unroll
            for (int fr = 0; fr < 2; ++fr)
                acc[fr][fc] = __builtin_amdgcn_mfma_f32_16x16x32_bf16(
                    afr[cur][fr], bv, acc[fr][fc], 0, 0, 0);
        }
    }

    if (tid < 64) { vsL[tid]=evs; voL[tid]=evo; dcL[tid]=edc; dtfL[tid]=edtf; }
    __syncthreads();

    #pragma unroll
    for (int fr = 0; fr < 2; ++fr) {
        #pragma unroll
        for (int r = 0; r < 4; ++r) {
            int ol = wr*32 + fr*16 + quad*4 + r;
            int o = o0 + ol;
            float vs = vsL[ol], vo = voL[ol], dcv = dcL[ol];
            const size_t orow = xbase + (size_t)o*NSP;
            #pragma unroll
            for (int fc = 0; fc < 2; ++fc) {
                int nl = wc*32 + fc*16 + l16;
                int nn = n0 + nl;
                if (nn < NSP) {
                    size_t gi = orow + nn;
                    out[gi] = (acc[fr][fc][r]*vs + vo)*(dcv + dtfL[nl]) + x[gi];
                }
            }
        }
    }
}

// --------------------- fallback main GEMM (LDS-staged, double-buffered)
template<int WBF>
__global__ __launch_bounds__(256) void main_kernel(
    const float* __restrict__ x, const float* __restrict__ vw,
    const float* __restrict__ ws, float* __restrict__ out)
{
    __shared__ u16 Ws[2][4096];
    __shared__ unsigned int Xs[2][2048];
    __shared__ float vsL[128], voL[128], dcL[128], dtfL[128];

    int tid = threadIdx.x;
    int flat = blockIdx.x;
    int xcd = flat & 7, idx = flat >> 3;
    int pair = xcd*56 + (idx >> 1);
    int o0 = (idx & 1) * 128;
    int n0 = (pair % 14) * 128;
    int b  = pair / 14;
    const size_t xbase = (size_t)b * NC * NSP;

    if (tid < 128) {
        int o = o0 + tid;
        vsL[tid] = ws[OFF_VSC+o];
        voL[tid] = ws[OFF_VOF+o];
        dcL[tid] = ws[OFF_DC+o];
        int nn = n0 + tid; if (nn > NSP-1) nn = NSP-1;
        int ff = nn / NT, tt = nn - ff*NT;
        dtfL[tid] = ws[OFF_DT+ff] + ws[OFF_DF+tt];
    }

    int wv = tid >> 6, ln = tid & 63;
    int quad = ln >> 4, l16 = ln & 15;
    int wr = wv >> 1, wc = wv & 1;

    float4v acc[4][4] = {};

    int kgs = tid >> 5, nbs = tid & 31;
    int oo = tid >> 1, half = tid & 1;

    const u16* wbg = nullptr;
    if constexpr (WBF) wbg = (const u16*)(ws + OFF_WB16) + (size_t)(o0 >> 7) * 32768;

    int4v wA, wB;
    float wf[16];
    float xv[4][4];

    auto loadW = [&](int ks) {
        if constexpr (WBF) {
            const int4v* wsrc = (const int4v*)(wbg + (size_t)ks*4096);
            wA = wsrc[tid]; wB = wsrc[256 + tid];
        } else {
            const float* wr4 = vw + (size_t)(o0+oo)*NC + ks*32 + half*16;
            #pragma unroll
            for (int c = 0; c < 16; ++c) wf[c] = wr4[c];
        }
    };
    auto loadX = [&](int ks) {
        int nbase = n0 + nbs*4;
        const float* xr = x + xbase + (size_t)(ks*32 + kgs*4)*NSP + nbase;
        if (nbase + 3 < NSP) {
            #pragma unroll
            for (int rr = 0; rr < 4; ++rr)
                #pragma unroll
                for (int i = 0; i < 4; ++i)
                    xv[rr][i] = xr[(size_t)rr*NSP + i];
        } else {
            #pragma unroll
            for (int rr = 0; rr < 4; ++rr)
                #pragma unroll
                for (int i = 0; i < 4; ++i)
                    xv[rr][i] = (nbase + i < NSP) ? xr[(size_t)rr*NSP + i] : 0.f;
        }
    };
    auto storeWX = [&](int bufi) {
        if constexpr (WBF) {
            *(int4v*)&Ws[bufi][tid*8]        = wA;
            *(int4v*)&Ws[bufi][2048 + tid*8] = wB;
        } else {
            union { u16 us[16]; short8 v[2]; } wb;
            #pragma unroll
            for (int c = 0; c < 16; ++c) wb.us[c] = f2b(wf[c]);
            int frg = oo >> 4, o16 = oo & 15;
            #pragma unroll
            for (int qq = 0; qq < 2; ++qq) {
                int qd = 2*half + qq;
                *(short8*)&Ws[bufi][frg*512 + qd*128 + o16*8] = wb.v[qq];
            }
        }
        unsigned int pk[8];
        #pragma unroll
        for (int i = 0; i < 4; ++i)
            #pragma unroll
            for (int jp = 0; jp < 2; ++jp)
                pk[i*2+jp] = pk2(xv[2*jp][i], xv[2*jp+1][i]);
        *(int4v*)&Xs[bufi][XSW(kgs, nbs*8)]     = *(int4v*)&pk[0];
        *(int4v*)&Xs[bufi][XSW(kgs, nbs*8 + 4)] = *(int4v*)&pk[4];
    };

    loadW(0); loadX(0);
    storeWX(0);
    __syncthreads();

    for (int ks = 0; ks < 8; ++ks) {
        int cur = ks & 1;
        if (ks < 7) { loadW(ks+1); loadX(ks+1); }

        short8 afr[4], bfr[4];
        #pragma unroll
        for (int fr = 0; fr < 4; ++fr)
            afr[fr] = *(short8*)&Ws[cur][(wr*4+fr)*512 + ln*8];
        #pragma unroll
        for (int fc = 0; fc < 4; ++fc) {
            int nn = wc*64 + fc*16 + l16;
            int2v lo = *(int2v*)&Xs[cur][XSW(2*quad,   2*nn)];
            int2v hi = *(int2v*)&Xs[cur][XSW(2*quad+1, 2*nn)];
            union { int i4[4]; short8 v; } u;
            u.i4[0] = lo.x; u.i4[1] = lo.y; u.i4[2] = hi.x; u.i4[3] = hi.y;
            bfr[fc] = u.v;
        }
        #pragma unroll
        for (int fr = 0; fr < 4; ++fr)
            #pragma unroll
            for (int fc = 0; fc < 4; ++fc)
                acc[fr][fc] = __builtin_amdgcn_mfma_f32_16x16x32_bf16(
                    afr[fr], bfr[fc], acc[fr][fc], 0, 0, 0);

        if (ks < 7) storeWX(cur ^ 1);
        __syncthreads();
    }

    #pragma unroll
    for (int fr = 0; fr < 4; ++fr) {
        #pragma unroll
        for (int r = 0; r < 4; ++r) {
            int ol = wr*64 + fr*16 + quad*4 + r;
            int o = o0 + ol;
            float vs = vsL[ol], vo = voL[ol], dcv = dcL[ol];
            const size_t orow = xbase + (size_t)o*NSP;
            #pragma unroll
            for (int fc = 0; fc < 4; ++fc) {
                int nl = wc*64 + fc*16 + l16;
                int nn = n0 + nl;
                if (nn < NSP) {
                    size_t gi = orow + nn;
                    out[gi] = (acc[fr][fc][r]*vs + vo)*(dcv + dtfL[nl]) + x[gi];
                }
            }
        }
    }
}

extern "C" void kernel_launch(void* const* d_in, const int* in_sizes, int n_in,
                              void* d_out, int out_size, void* d_ws, size_t ws_size,
                              hipStream_t stream)
{
    const float* x    = (const float*)d_in[0];
    const float* qc_w = (const float*)d_in[1];  const float* qc_bn = (const float*)d_in[2];
    const float* kc_w = (const float*)d_in[3];  const float* kc_bn = (const float*)d_in[4];
    const float* lc_bn= (const float*)d_in[5];
    const float* qf_w = (const float*)d_in[6];  const float* qf_bn = (const float*)d_in[7];
    const float* kf_w = (const float*)d_in[8];  const float* kf_bn = (const float*)d_in[9];
    const float* lf_bn= (const float*)d_in[10];
    const float* qt_w = (const float*)d_in[11]; const float* qt_bn = (const float*)d_in[12];
    const float* kt_w = (const float*)d_in[13]; const float* kt_bn = (const float*)d_in[14];
    const float* lt_bn= (const float*)d_in[15];
    const float* v_w  = (const float*)d_in[16]; const float* v_b   = (const float*)d_in[17];
    const float* v_bn = (const float*)d_in[18];
    float* ws = (float*)d_ws;
    float* out = (float*)d_out;

    int fuse_t = (ws_size >= (size_t)WS2_END * sizeof(float)) ? 1 : 0;
    int wbf    = (ws_size >= (size_t)WS3_END * sizeof(float)) ? 1 : 0;
    int newq   = (ws_size >= (size_t)WS4_END * sizeof(float)) ? 1 : 0;
    int xb     = (ws_size >= (size_t)WS5_END * sizeof(float)) ? 1 : 0;

    prep_kernel<<<wbf ? 37 : 25, 256, 0, stream>>>(qc_w,qc_bn,kc_w,kc_bn,lc_bn,
                                                   qf_w,qf_bn,kf_w,kf_bn,lf_bn,
                                                   qt_w,qt_bn,kt_w,kt_bn,lt_bn,
                                                   v_b,v_bn,v_w,ws,newq);
    if (newq) {
        qv_kernel<<<4480, 512, 0, stream>>>(x, ws, xb);
        sm_kernel<<<256, 256, 0, stream>>>(ws);
    } else {
        qkt_kernel<<<NB*NF*2, 512, 0, stream>>>(x, ws, fuse_t);
        if (fuse_t) tsm_kernel<<<NB, 256, 0, stream>>>(ws);
        else        t_kernel<<<NB*8, 256, 0, stream>>>(x, ws);
    }
    if (xb && wbf)
        main2_kernel<<<3584, 256, 0, stream>>>(x, ws, out);
    else if (wbf)
        main_kernel<1><<<896, 256, 0, stream>>>(x, v_w, ws, out);
    else
        main_kernel<0><<<896, 256, 0, stream>>>(x, v_w, ws, out);
}